// Round 2
// baseline (3838.017 us; speedup 1.0000x reference)
//
#include <hip/hip_runtime.h>

typedef __attribute__((ext_vector_type(8))) short short8;
typedef __attribute__((ext_vector_type(4))) float f32x4;
typedef __attribute__((ext_vector_type(4))) unsigned short ushort4v;
typedef unsigned short ushortT;

#define PADROWS 4098
#define HSTR 2056   // half-spectrum row stride (float2), 64B-aligned

__device__ __forceinline__ ushortT f2bf(float f) {
  union { float f; unsigned int u; } v; v.f = f;
  unsigned int r = (v.u + 0x7FFFu + ((v.u >> 16) & 1u)) >> 16;
  return (ushortT)r;
}
__device__ __forceinline__ float bf2f(ushortT b) {
  union { unsigned int u; float f; } v; v.u = ((unsigned int)b) << 16;
  return v.f;
}

__device__ __forceinline__ void gl2lds16(const void* g, void* l) {
  __builtin_amdgcn_global_load_lds((const __attribute__((address_space(1))) void*)g,
                                   (__attribute__((address_space(3))) void*)l, 16, 0, 0);
}

// ---------------- conversions ----------------

__global__ void convert_u(const float* __restrict__ in, ushortT* __restrict__ outb) {
  size_t idx = (size_t)blockIdx.x * 256 + threadIdx.x;  // one per 4 elems
  f32x4 v = *(const f32x4*)(in + idx * 4);
  ushort4v r;
  r[0] = f2bf(v[0]); r[1] = f2bf(v[1]); r[2] = f2bf(v[2]); r[3] = f2bf(v[3]);
  *(ushort4v*)(outb + idx * 4) = r;
}

// pW (512,2048) f32 -> pWt (2048,512) bf16
__global__ void convert_pW(const float* __restrict__ pW, ushortT* __restrict__ pWt) {
  __shared__ float tile[32][33];
  int rt = blockIdx.y * 32;   // row in pW (i)
  int ct = blockIdx.x * 32;   // col in pW (o)
  int tx = threadIdx.x, ty = threadIdx.y;
#pragma unroll
  for (int q = 0; q < 32; q += 8)
    tile[ty + q][tx] = pW[(size_t)(rt + ty + q) * 2048 + ct + tx];
  __syncthreads();
#pragma unroll
  for (int q = 0; q < 32; q += 8)
    pWt[(size_t)(ct + ty + q) * 512 + rt + tx] = f2bf(tile[tx][ty + q]);
}

// cW (2048,2048,3) f32 -> Wt[h][o][i] bf16
__global__ void convert_cW(const float* __restrict__ cW, ushortT* __restrict__ Wt) {
  size_t idx = (size_t)blockIdx.x * 256 + threadIdx.x;  // (o,i)
  const float* p = cW + idx * 3;
  float w0 = p[0], w1 = p[1], w2 = p[2];
  Wt[idx]           = f2bf(w0);
  Wt[idx + 4194304] = f2bf(w1);
  Wt[idx + 8388608] = f2bf(w2);
}

__global__ void zero_pad(ushortT* __restrict__ Apad) {
  int idx = blockIdx.x * 256 + threadIdx.x;   // 16384 = 4b * 2r * 2048i
  int i = idx & 2047;
  int r = (idx >> 11) & 1;
  int b = idx >> 12;
  Apad[((size_t)b * PADROWS + (r ? 4097 : 0)) * 2048 + i] = 0;
}

// tT[128][4096], window[4096]
__global__ void pe_window(float* __restrict__ tT, float* __restrict__ window) {
  int idx = blockIdx.x * 256 + threadIdx.x;  // 262144
  int l = idx & 4095, d2 = idx >> 12;        // d2 in 0..63
  float dv = expf(-9.210340371976184f * (float)(2 * d2) / 128.0f);
  float ang = (float)l * dv;
  tT[(size_t)(2 * d2) * 4096 + l] = sinf(ang);
  tT[(size_t)(2 * d2 + 1) * 4096 + l] = cosf(ang);
  if (d2 == 0)
    window[l] = 0.5f * (1.0f - cosf(6.283185307179586f * (float)l / 4095.0f));
}

// ---------------- GEMM 1: hat_z = u @ pW + pb -> Apad (padded, bf16) ----------------

__launch_bounds__(256, 2)
__global__ void gemm_A(const ushortT* __restrict__ u_bf, const ushortT* __restrict__ pWt,
                       const float* __restrict__ pb, ushortT* __restrict__ Apad) {
  __shared__ alignas(16) ushortT As[128 * 64];
  __shared__ alignas(16) ushortT Bs[128 * 64];
  const int tid = threadIdx.x;
  const int lane = tid & 63, w = tid >> 6;
  const int wm = w >> 1, wn = w & 1;
  const int tm = blockIdx.x, tn = blockIdx.y;
  f32x4 acc[4][4] = {};
#pragma unroll 1
  for (int kt = 0; kt < 8; ++kt) {
    const int i0 = kt * 64;
#pragma unroll
    for (int i = 0; i < 4; ++i) {
      int ldsoff = (i * 4 + w) * 1024;            // bytes, wave-uniform
      int m = ((i * 4 + w) << 3) + (lane >> 3);   // tile row 0..127
      int col = (lane & 7) * 8;                   // k-offset (bf16 elems), linear
      gl2lds16(u_bf + (size_t)(tm * 128 + m) * 512 + i0 + col, (char*)As + ldsoff);
      gl2lds16(pWt  + (size_t)(tn * 128 + m) * 512 + i0 + col, (char*)Bs + ldsoff);
    }
    __syncthreads();
#pragma unroll
    for (int ks = 0; ks < 2; ++ks) {
      short8 av[4], bv[4];
#pragma unroll
      for (int mi = 0; mi < 4; ++mi) {
        int row = wm * 64 + mi * 16 + (lane & 15);
        av[mi] = *(const short8*)(As + row * 64 + (ks * 4 + (lane >> 4)) * 8);
      }
#pragma unroll
      for (int ni = 0; ni < 4; ++ni) {
        int row = wn * 64 + ni * 16 + (lane & 15);
        bv[ni] = *(const short8*)(Bs + row * 64 + (ks * 4 + (lane >> 4)) * 8);
      }
#pragma unroll
      for (int mi = 0; mi < 4; ++mi)
#pragma unroll
        for (int ni = 0; ni < 4; ++ni)
          acc[mi][ni] = __builtin_amdgcn_mfma_f32_16x16x32_bf16(av[mi], bv[ni], acc[mi][ni], 0, 0, 0);
    }
    __syncthreads();
  }
#pragma unroll
  for (int mi = 0; mi < 4; ++mi)
#pragma unroll
    for (int ni = 0; ni < 4; ++ni) {
      int gc = tn * 128 + wn * 64 + ni * 16 + (lane & 15);
      float bias = pb[gc];
#pragma unroll
      for (int j = 0; j < 4; ++j) {
        int gl = tm * 128 + wm * 64 + mi * 16 + (lane >> 4) * 4 + j;
        int b = gl >> 12;
        Apad[((size_t)b * PADROWS + (gl & 4095) + 1) * 2048 + gc] = f2bf(acc[mi][ni][j] + bias);
      }
    }
}

// ---------------- GEMM 2: 3-tap conv, TRANSPOSED output (vT / projsT direct) ----------------

__launch_bounds__(256, 2)
__global__ void gemm_conv(const ushortT* __restrict__ Apad, const ushortT* __restrict__ Wt,
                          const float* __restrict__ cb, float* __restrict__ vT,
                          ushortT* __restrict__ projsT) {
  __shared__ alignas(16) ushortT As[128 * 64];
  __shared__ alignas(16) ushortT Bs[128 * 64];
  const int tid = threadIdx.x;
  const int lane = tid & 63, w = tid >> 6;
  const int wm = w >> 1, wn = w & 1;
  const int tm = blockIdx.x, tn = blockIdx.y;
  const int b = tm >> 5;
  const int l0 = (tm & 31) * 128;
  f32x4 acc[4][4] = {};   // [ni][mi] — transposed accumulation
#pragma unroll 1
  for (int kt = 0; kt < 96; ++kt) {
    const int h = kt >> 5;
    const int i0 = (kt & 31) << 6;
    const size_t arow = (size_t)b * PADROWS + l0 + h;
#pragma unroll
    for (int i = 0; i < 4; ++i) {
      int ldsoff = (i * 4 + w) * 1024;
      int m = ((i * 4 + w) << 3) + (lane >> 3);
      int col = (lane & 7) * 8;
      gl2lds16(Apad + (arow + m) * 2048 + i0 + col, (char*)As + ldsoff);
      gl2lds16(Wt + ((size_t)(h * 2048 + tn * 128 + m)) * 2048 + i0 + col, (char*)Bs + ldsoff);
    }
    __syncthreads();
#pragma unroll
    for (int ks = 0; ks < 2; ++ks) {
      short8 av[4], bv[4];
#pragma unroll
      for (int mi = 0; mi < 4; ++mi) {
        int row = wm * 64 + mi * 16 + (lane & 15);
        av[mi] = *(const short8*)(As + row * 64 + (ks * 4 + (lane >> 4)) * 8);
      }
#pragma unroll
      for (int ni = 0; ni < 4; ++ni) {
        int row = wn * 64 + ni * 16 + (lane & 15);
        bv[ni] = *(const short8*)(Bs + row * 64 + (ks * 4 + (lane >> 4)) * 8);
      }
      // D^T: pass B-fragment as A-operand -> acc[ni][mi] = (Wt · A^T) tile
#pragma unroll
      for (int mi = 0; mi < 4; ++mi)
#pragma unroll
        for (int ni = 0; ni < 4; ++ni)
          acc[ni][mi] = __builtin_amdgcn_mfma_f32_16x16x32_bf16(bv[ni], av[mi], acc[ni][mi], 0, 0, 0);
    }
    __syncthreads();
  }
  // D^T layout: col (lane&15) = l-side, row ((lane>>4)*4+j) = o-side
#pragma unroll
  for (int ni = 0; ni < 4; ++ni)
#pragma unroll
    for (int mi = 0; mi < 4; ++mi) {
      int l = l0 + wm * 64 + mi * 16 + (lane & 15);
#pragma unroll
      for (int j = 0; j < 4; ++j) {
        int o = tn * 128 + wn * 64 + ni * 16 + (lane >> 4) * 4 + j;
        float val = acc[ni][mi][j] + cb[o];
        if (o < 512) {
          vT[((size_t)b * 512 + o) * 4096 + l] = val;
        } else {
          int oc = o - 512;
          int k = oc >> 9, c = oc & 511;
          projsT[((size_t)(k * 4 + b) * 512 + c) * 4096 + l] = f2bf(val);
        }
      }
    }
}

// ---------------- filters ----------------

__launch_bounds__(256)
__global__ void h_kernel(const float* __restrict__ tT, const float* __restrict__ fW,
                         const float* __restrict__ fb, const float* __restrict__ window,
                         float* __restrict__ hT) {
  __shared__ float tTs[128][32];
  int l0 = blockIdx.x * 32;
  int tid = threadIdx.x;
  for (int r = tid; r < 128 * 32; r += 256) {
    int d = r >> 5, li = r & 31;
    tTs[d][li] = tT[(size_t)d * 4096 + l0 + li];
  }
  __syncthreads();
  int li = tid & 31, cq = tid >> 5;
  float wl = window[l0 + li];
  for (int ch = cq; ch < 1536; ch += 8) {
    float acc = 0.f;
#pragma unroll
    for (int d = 0; d < 128; ++d)
      acc = fmaf(tTs[d][li], fW[d * 1536 + ch], acc);
    hT[(size_t)ch * 4096 + l0 + li] = (acc + fb[ch]) * wl;
  }
}

// ---------------- FFT (Stockham radix-2, N=4096, complex) ----------------

__device__ void fft_core(float2* sA, float2* sB, int tid, float dirpi) {
  float2* src = sA;
  float2* dst = sB;
#pragma unroll 1
  for (int s = 0; s < 12; ++s) {
    const int m = 1 << s;
    const int lh = 2048 >> s;
    const float w0 = dirpi / (float)lh;
#pragma unroll
    for (int p = tid; p < 2048; p += 256) {
      int j = p >> s;
      int jm = p & ~(m - 1);
      float2 a = src[p];
      float2 c = src[p + 2048];
      float sn, cs;
      __sincosf(w0 * (float)j, &sn, &cs);
      float dx = a.x - c.x, dy = a.y - c.y;
      dst[p + jm] = make_float2(a.x + c.x, a.y + c.y);
      dst[p + jm + m] = make_float2(dx * cs - dy * sn, dx * sn + dy * cs);
    }
    __syncthreads();
    float2* t = src; src = dst; dst = t;
  }
}

__launch_bounds__(256, 1)
__global__ void fft_filter(const float* __restrict__ hT, float2* __restrict__ Hf) {
  __shared__ float2 X[4096];
  __shared__ float2 Y[4096];
  int ch = blockIdx.x;
  const float* sig = hT + (size_t)ch * 4096;
  for (int i = threadIdx.x; i < 4096; i += 256) X[i] = make_float2(sig[i], 0.f);
  __syncthreads();
  fft_core(X, Y, threadIdx.x, -3.14159265358979323f);
  float2* o = Hf + (size_t)ch * HSTR;
  for (int i = threadIdx.x; i <= 2048; i += 256) o[i] = X[i];   // half spectrum
}

__launch_bounds__(256, 1)
__global__ void fft_conv(float* __restrict__ vT, const ushortT* __restrict__ projsT,
                         const float2* __restrict__ Hf, int k) {
  __shared__ float2 X[4096];
  __shared__ float2 Y[4096];
  int bc = blockIdx.x;   // b*512 + c
  int c = bc & 511, b = bc >> 9;
  int tid = threadIdx.x;
  float* sig = vT + (size_t)bc * 4096;
  for (int i = tid; i < 4096; i += 256) X[i] = make_float2(sig[i], 0.f);
  __syncthreads();
  fft_core(X, Y, tid, -3.14159265358979323f);
  const float2* H = Hf + ((size_t)k * 512 + c) * HSTR;
  for (int i = tid; i < 4096; i += 256) {
    float2 x = X[i], h;
    if (i <= 2048) h = H[i];
    else { float2 t = H[4096 - i]; h = make_float2(t.x, -t.y); }  // conj symmetry
    X[i] = make_float2(x.x * h.x - x.y * h.y, x.x * h.y + x.y * h.x);
  }
  __syncthreads();
  fft_core(X, Y, tid, 3.14159265358979323f);
  const ushortT* xn = projsT + ((size_t)(k * 4 + b) * 512 + c) * 4096;
  const float scale = 1.0f / 4096.0f;
  for (int i = tid; i < 4096; i += 256)
    sig[i] = X[i].x * scale * bf2f(xn[i]);
}

// ---------------- output GEMM ----------------

__launch_bounds__(256)
__global__ void out_gemm(const float* __restrict__ vT, const float* __restrict__ oW,
                         const float* __restrict__ ob, float* __restrict__ out) {
  int l0 = blockIdx.x * 64;
  int b = l0 >> 12;
  int li = threadIdx.x & 63;
  int og = threadIdx.x >> 6;   // 0..3
  float acc[8] = {};
  const float* vb = vT + (size_t)b * 512 * 4096 + (l0 & 4095) + li;
#pragma unroll 1
  for (int c = 0; c < 512; ++c) {
    float v = vb[(size_t)c * 4096];
#pragma unroll
    for (int j = 0; j < 8; ++j)
      acc[j] = fmaf(v, oW[c * 32 + og * 8 + j], acc[j]);
  }
  float* op = out + (size_t)(l0 + li) * 32 + og * 8;
  f32x4 r0, r1;
  r0[0] = acc[0] + ob[og * 8 + 0]; r0[1] = acc[1] + ob[og * 8 + 1];
  r0[2] = acc[2] + ob[og * 8 + 2]; r0[3] = acc[3] + ob[og * 8 + 3];
  r1[0] = acc[4] + ob[og * 8 + 4]; r1[1] = acc[5] + ob[og * 8 + 5];
  r1[2] = acc[6] + ob[og * 8 + 6]; r1[3] = acc[7] + ob[og * 8 + 7];
  *(f32x4*)op = r0;
  *(f32x4*)(op + 4) = r1;
}

// ---------------- diagnostics ----------------

__global__ void ws_sentinel(float* __restrict__ out) {
  if (threadIdx.x == 0) out[0] = -31337.0f;
}

// ---------------- launch ----------------

extern "C" void kernel_launch(void* const* d_in, const int* in_sizes, int n_in,
                              void* d_out, int out_size, void* d_ws, size_t ws_size,
                              hipStream_t stream) {
  (void)in_sizes; (void)n_in; (void)out_size;
  const float* u  = (const float*)d_in[0];
  const float* pW = (const float*)d_in[1];
  const float* pb = (const float*)d_in[2];
  const float* cW = (const float*)d_in[3];
  const float* cb = (const float*)d_in[4];
  const float* fW = (const float*)d_in[5];
  const float* fb = (const float*)d_in[6];
  const float* oW = (const float*)d_in[7];
  const float* ob = (const float*)d_in[8];
  float* out = (float*)d_out;

  char* ws = (char*)d_ws;
  // persistent region
  ushortT* Apad   = (ushortT*)(ws);                    // 67,141,632  (4x4098x2048 bf16)
  ushortT* Wt     = (ushortT*)(ws + 67141632);         // 25,165,824  (3x2048x2048 bf16)
  float2*  Hf     = (float2*) (ws + 92307456);         // 25,264,128  (1536 x HSTR c64, half-spectrum)
  float*   vT     = (float*)  (ws + 117571584);        // 33,554,432  (4x512x4096 f32)
  ushortT* projsT = (ushortT*)(ws + 151126016);        // 50,331,648  (12x512x4096 bf16)
  const size_t total = 201457664;                      // 192.1 MiB
  // scratch overlay on [vT, end) — all dead before gemm_conv writes vT/projsT
  char* S = (char*)vT;
  ushortT* u_bf   = (ushortT*)(S);                     // 16,777,216
  ushortT* pWt    = (ushortT*)(S + 16777216);          //  2,097,152
  float*   tT     = (float*)  (S + 18874368);          //  2,097,152
  float*   window = (float*)  (S + 20971520);          //     16,384
  float*   hT     = (float*)  (S + 20987904);          // 25,165,824 -> ends 46,153,728 (< 83,886,080)

  if (total > ws_size) {           // diagnostic: distinguishable failure signature
    ws_sentinel<<<1, 64, 0, stream>>>(out);
    return;
  }

  convert_u<<<8192, 256, 0, stream>>>(u, u_bf);
  convert_pW<<<dim3(64, 16), dim3(32, 8), 0, stream>>>(pW, pWt);
  convert_cW<<<16384, 256, 0, stream>>>(cW, Wt);
  zero_pad<<<64, 256, 0, stream>>>(Apad);
  pe_window<<<1024, 256, 0, stream>>>(tT, window);
  gemm_A<<<dim3(128, 16), 256, 0, stream>>>(u_bf, pWt, pb, Apad);       // u_bf,pWt dead after
  h_kernel<<<128, 256, 0, stream>>>(tT, fW, fb, window, hT);            // tT,window dead after
  fft_filter<<<1536, 256, 0, stream>>>(hT, Hf);                         // hT dead after
  gemm_conv<<<dim3(128, 16), 256, 0, stream>>>(Apad, Wt, cb, vT, projsT);
  for (int k = 0; k < 3; ++k)
    fft_conv<<<2048, 256, 0, stream>>>(vT, projsT, Hf, k);
  out_gemm<<<256, 256, 0, stream>>>(vT, oW, ob, out);
}

// Round 3
// 1063.997 us; speedup vs baseline: 3.6072x; 3.6072x over previous
//
#include <hip/hip_runtime.h>

typedef __attribute__((ext_vector_type(8))) short short8;
typedef __attribute__((ext_vector_type(4))) float f32x4;
typedef __attribute__((ext_vector_type(4))) unsigned short ushort4v;
typedef unsigned short ushortT;

#define PADROWS 4098
#define HSTR 2056   // half-spectrum row stride (float2), 64B-aligned

__device__ __forceinline__ ushortT f2bf(float f) {
  union { float f; unsigned int u; } v; v.f = f;
  unsigned int r = (v.u + 0x7FFFu + ((v.u >> 16) & 1u)) >> 16;
  return (ushortT)r;
}
__device__ __forceinline__ float bf2f(ushortT b) {
  union { unsigned int u; float f; } v; v.u = ((unsigned int)b) << 16;
  return v.f;
}

__device__ __forceinline__ void gl2lds16(const void* g, void* l) {
  __builtin_amdgcn_global_load_lds((const __attribute__((address_space(1))) void*)g,
                                   (__attribute__((address_space(3))) void*)l, 16, 0, 0);
}

// ---------------- conversions ----------------

__global__ void convert_u(const float* __restrict__ in, ushortT* __restrict__ outb) {
  size_t idx = (size_t)blockIdx.x * 256 + threadIdx.x;  // one per 4 elems
  f32x4 v = *(const f32x4*)(in + idx * 4);
  ushort4v r;
  r[0] = f2bf(v[0]); r[1] = f2bf(v[1]); r[2] = f2bf(v[2]); r[3] = f2bf(v[3]);
  *(ushort4v*)(outb + idx * 4) = r;
}

// pW (512,2048) f32 -> pWt (2048,512) bf16
__global__ void convert_pW(const float* __restrict__ pW, ushortT* __restrict__ pWt) {
  __shared__ float tile[32][33];
  int rt = blockIdx.y * 32;   // row in pW (i)
  int ct = blockIdx.x * 32;   // col in pW (o)
  int tx = threadIdx.x, ty = threadIdx.y;
#pragma unroll
  for (int q = 0; q < 32; q += 8)
    tile[ty + q][tx] = pW[(size_t)(rt + ty + q) * 2048 + ct + tx];
  __syncthreads();
#pragma unroll
  for (int q = 0; q < 32; q += 8)
    pWt[(size_t)(ct + ty + q) * 512 + rt + tx] = f2bf(tile[tx][ty + q]);
}

// cW (2048,2048,3) f32 -> Wt[h][o][i] bf16
__global__ void convert_cW(const float* __restrict__ cW, ushortT* __restrict__ Wt) {
  size_t idx = (size_t)blockIdx.x * 256 + threadIdx.x;  // (o,i)
  const float* p = cW + idx * 3;
  float w0 = p[0], w1 = p[1], w2 = p[2];
  Wt[idx]           = f2bf(w0);
  Wt[idx + 4194304] = f2bf(w1);
  Wt[idx + 8388608] = f2bf(w2);
}

__global__ void zero_pad(ushortT* __restrict__ Apad) {
  int idx = blockIdx.x * 256 + threadIdx.x;   // 16384 = 4b * 2r * 2048i
  int i = idx & 2047;
  int r = (idx >> 11) & 1;
  int b = idx >> 12;
  Apad[((size_t)b * PADROWS + (r ? 4097 : 0)) * 2048 + i] = 0;
}

// tT[128][4096], window[4096]
__global__ void pe_window(float* __restrict__ tT, float* __restrict__ window) {
  int idx = blockIdx.x * 256 + threadIdx.x;  // 262144
  int l = idx & 4095, d2 = idx >> 12;        // d2 in 0..63
  float dv = expf(-9.210340371976184f * (float)(2 * d2) / 128.0f);
  float ang = (float)l * dv;
  tT[(size_t)(2 * d2) * 4096 + l] = sinf(ang);
  tT[(size_t)(2 * d2 + 1) * 4096 + l] = cosf(ang);
  if (d2 == 0)
    window[l] = 0.5f * (1.0f - cosf(6.283185307179586f * (float)l / 4095.0f));
}

// ---------------- GEMM 1: hat_z = u @ pW + pb -> Apad (padded, bf16) ----------------

__launch_bounds__(256, 2)
__global__ void gemm_A(const ushortT* __restrict__ u_bf, const ushortT* __restrict__ pWt,
                       const float* __restrict__ pb, ushortT* __restrict__ Apad) {
  __shared__ alignas(16) ushortT As[128 * 64];
  __shared__ alignas(16) ushortT Bs[128 * 64];
  const int tid = threadIdx.x;
  const int lane = tid & 63, w = tid >> 6;
  const int wm = w >> 1, wn = w & 1;
  const int tm = blockIdx.x, tn = blockIdx.y;
  f32x4 acc[4][4] = {};
#pragma unroll 1
  for (int kt = 0; kt < 8; ++kt) {
    const int i0 = kt * 64;
#pragma unroll
    for (int i = 0; i < 4; ++i) {
      int ldsoff = (i * 4 + w) * 1024;            // bytes, wave-uniform
      int m = ((i * 4 + w) << 3) + (lane >> 3);   // tile row 0..127
      int col = (lane & 7) * 8;                   // k-offset (bf16 elems), linear
      gl2lds16(u_bf + (size_t)(tm * 128 + m) * 512 + i0 + col, (char*)As + ldsoff);
      gl2lds16(pWt  + (size_t)(tn * 128 + m) * 512 + i0 + col, (char*)Bs + ldsoff);
    }
    __syncthreads();
#pragma unroll
    for (int ks = 0; ks < 2; ++ks) {
      short8 av[4], bv[4];
#pragma unroll
      for (int mi = 0; mi < 4; ++mi) {
        int row = wm * 64 + mi * 16 + (lane & 15);
        av[mi] = *(const short8*)(As + row * 64 + (ks * 4 + (lane >> 4)) * 8);
      }
#pragma unroll
      for (int ni = 0; ni < 4; ++ni) {
        int row = wn * 64 + ni * 16 + (lane & 15);
        bv[ni] = *(const short8*)(Bs + row * 64 + (ks * 4 + (lane >> 4)) * 8);
      }
#pragma unroll
      for (int mi = 0; mi < 4; ++mi)
#pragma unroll
        for (int ni = 0; ni < 4; ++ni)
          acc[mi][ni] = __builtin_amdgcn_mfma_f32_16x16x32_bf16(av[mi], bv[ni], acc[mi][ni], 0, 0, 0);
    }
    __syncthreads();
  }
#pragma unroll
  for (int mi = 0; mi < 4; ++mi)
#pragma unroll
    for (int ni = 0; ni < 4; ++ni) {
      int gc = tn * 128 + wn * 64 + ni * 16 + (lane & 15);
      float bias = pb[gc];
#pragma unroll
      for (int j = 0; j < 4; ++j) {
        int gl = tm * 128 + wm * 64 + mi * 16 + (lane >> 4) * 4 + j;
        int b = gl >> 12;
        Apad[((size_t)b * PADROWS + (gl & 4095) + 1) * 2048 + gc] = f2bf(acc[mi][ni][j] + bias);
      }
    }
}

// ---------------- GEMM 2: 3-tap conv, TRANSPOSED output (vT / projsT direct) ----------------

__launch_bounds__(256, 2)
__global__ void gemm_conv(const ushortT* __restrict__ Apad, const ushortT* __restrict__ Wt,
                          const float* __restrict__ cb, float* __restrict__ vT,
                          ushortT* __restrict__ projsT) {
  __shared__ alignas(16) ushortT As[128 * 64];
  __shared__ alignas(16) ushortT Bs[128 * 64];
  const int tid = threadIdx.x;
  const int lane = tid & 63, w = tid >> 6;
  const int wm = w >> 1, wn = w & 1;
  const int tm = blockIdx.x, tn = blockIdx.y;
  const int b = tm >> 5;
  const int l0 = (tm & 31) * 128;
  f32x4 acc[4][4] = {};   // [ni][mi] — transposed accumulation
#pragma unroll 1
  for (int kt = 0; kt < 96; ++kt) {
    const int h = kt >> 5;
    const int i0 = (kt & 31) << 6;
    const size_t arow = (size_t)b * PADROWS + l0 + h;
#pragma unroll
    for (int i = 0; i < 4; ++i) {
      int ldsoff = (i * 4 + w) * 1024;
      int m = ((i * 4 + w) << 3) + (lane >> 3);
      int col = (lane & 7) * 8;
      gl2lds16(Apad + (arow + m) * 2048 + i0 + col, (char*)As + ldsoff);
      gl2lds16(Wt + ((size_t)(h * 2048 + tn * 128 + m)) * 2048 + i0 + col, (char*)Bs + ldsoff);
    }
    __syncthreads();
#pragma unroll
    for (int ks = 0; ks < 2; ++ks) {
      short8 av[4], bv[4];
#pragma unroll
      for (int mi = 0; mi < 4; ++mi) {
        int row = wm * 64 + mi * 16 + (lane & 15);
        av[mi] = *(const short8*)(As + row * 64 + (ks * 4 + (lane >> 4)) * 8);
      }
#pragma unroll
      for (int ni = 0; ni < 4; ++ni) {
        int row = wn * 64 + ni * 16 + (lane & 15);
        bv[ni] = *(const short8*)(Bs + row * 64 + (ks * 4 + (lane >> 4)) * 8);
      }
      // D^T: pass B-fragment as A-operand -> acc[ni][mi] = (Wt · A^T) tile
#pragma unroll
      for (int mi = 0; mi < 4; ++mi)
#pragma unroll
        for (int ni = 0; ni < 4; ++ni)
          acc[ni][mi] = __builtin_amdgcn_mfma_f32_16x16x32_bf16(bv[ni], av[mi], acc[ni][mi], 0, 0, 0);
    }
    __syncthreads();
  }
  // D^T layout: col (lane&15) = l-side, row ((lane>>4)*4+j) = o-side
#pragma unroll
  for (int ni = 0; ni < 4; ++ni)
#pragma unroll
    for (int mi = 0; mi < 4; ++mi) {
      int l = l0 + wm * 64 + mi * 16 + (lane & 15);
#pragma unroll
      for (int j = 0; j < 4; ++j) {
        int o = tn * 128 + wn * 64 + ni * 16 + (lane >> 4) * 4 + j;
        float val = acc[ni][mi][j] + cb[o];
        if (o < 512) {
          vT[((size_t)b * 512 + o) * 4096 + l] = val;
        } else {
          int oc = o - 512;
          int k = oc >> 9, c = oc & 511;
          projsT[((size_t)(k * 4 + b) * 512 + c) * 4096 + l] = f2bf(val);
        }
      }
    }
}

// ---------------- filter GEMM: hT[ch][l] = (t @ fW + fb)*window, f32, LDS-tiled ----------------
// grid (64, 12): l-tile 64, ch-tile 128. 96 KiB LDS. 4l x 8ch register block/thread.

__launch_bounds__(256, 1)
__global__ void h_kernel(const float* __restrict__ tT, const float* __restrict__ fW,
                         const float* __restrict__ fb, const float* __restrict__ window,
                         float* __restrict__ hT) {
  __shared__ float tTs[128][64];    // 32 KiB  [d][l]
  __shared__ float fWs[128][128];   // 64 KiB  [d][ch]
  const int l0 = blockIdx.x * 64;
  const int c0 = blockIdx.y * 128;
  const int tid = threadIdx.x;
  {
    int lq = (tid & 15) * 4;     // l offset in tile
    int dr = tid >> 4;           // 0..15
#pragma unroll
    for (int d = dr; d < 128; d += 16)
      *(f32x4*)(&tTs[d][lq]) = *(const f32x4*)(tT + (size_t)d * 4096 + l0 + lq);
  }
  {
    int cq = (tid & 31) * 4;     // ch offset in tile
    int dr = tid >> 5;           // 0..7
#pragma unroll
    for (int d = dr; d < 128; d += 8)
      *(f32x4*)(&fWs[d][cq]) = *(const f32x4*)(fW + (size_t)d * 1536 + c0 + cq);
  }
  __syncthreads();
  const int lgrp = tid & 15;     // 4 l's each
  const int cg = tid >> 4;       // 0..15, 8 ch each strided 16 (conflict-free)
  float acc[8][4] = {};
#pragma unroll 4
  for (int d = 0; d < 128; ++d) {
    f32x4 tv = *(const f32x4*)(&tTs[d][lgrp * 4]);
#pragma unroll
    for (int j = 0; j < 8; ++j) {
      float wv = fWs[d][cg + 16 * j];
      acc[j][0] = fmaf(tv[0], wv, acc[j][0]);
      acc[j][1] = fmaf(tv[1], wv, acc[j][1]);
      acc[j][2] = fmaf(tv[2], wv, acc[j][2]);
      acc[j][3] = fmaf(tv[3], wv, acc[j][3]);
    }
  }
  f32x4 wl = *(const f32x4*)(window + l0 + lgrp * 4);
#pragma unroll
  for (int j = 0; j < 8; ++j) {
    int ch = c0 + cg + 16 * j;
    float fbv = fb[ch];
    f32x4 r;
    r[0] = (acc[j][0] + fbv) * wl[0];
    r[1] = (acc[j][1] + fbv) * wl[1];
    r[2] = (acc[j][2] + fbv) * wl[2];
    r[3] = (acc[j][3] + fbv) * wl[3];
    *(f32x4*)(hT + (size_t)ch * 4096 + l0 + lgrp * 4) = r;
  }
}

// ---------------- FFT (Stockham radix-2, N=4096, complex) ----------------

__device__ void fft_core(float2* sA, float2* sB, int tid, float dirpi) {
  float2* src = sA;
  float2* dst = sB;
#pragma unroll 1
  for (int s = 0; s < 12; ++s) {
    const int m = 1 << s;
    const int lh = 2048 >> s;
    const float w0 = dirpi / (float)lh;
#pragma unroll
    for (int p = tid; p < 2048; p += 256) {
      int j = p >> s;
      int jm = p & ~(m - 1);
      float2 a = src[p];
      float2 c = src[p + 2048];
      float sn, cs;
      __sincosf(w0 * (float)j, &sn, &cs);
      float dx = a.x - c.x, dy = a.y - c.y;
      dst[p + jm] = make_float2(a.x + c.x, a.y + c.y);
      dst[p + jm + m] = make_float2(dx * cs - dy * sn, dx * sn + dy * cs);
    }
    __syncthreads();
    float2* t = src; src = dst; dst = t;
  }
}

__launch_bounds__(256, 1)
__global__ void fft_filter(const float* __restrict__ hT, float2* __restrict__ Hf) {
  __shared__ float2 X[4096];
  __shared__ float2 Y[4096];
  int ch = blockIdx.x;
  const float* sig = hT + (size_t)ch * 4096;
  for (int i = threadIdx.x; i < 4096; i += 256) X[i] = make_float2(sig[i], 0.f);
  __syncthreads();
  fft_core(X, Y, threadIdx.x, -3.14159265358979323f);
  float2* o = Hf + (size_t)ch * HSTR;
  for (int i = threadIdx.x; i <= 2048; i += 256) o[i] = X[i];   // half spectrum
}

__launch_bounds__(256, 1)
__global__ void fft_conv(float* __restrict__ vT, const ushortT* __restrict__ projsT,
                         const float2* __restrict__ Hf, int k) {
  __shared__ float2 X[4096];
  __shared__ float2 Y[4096];
  int bc = blockIdx.x;   // b*512 + c
  int c = bc & 511, b = bc >> 9;
  int tid = threadIdx.x;
  float* sig = vT + (size_t)bc * 4096;
  for (int i = tid; i < 4096; i += 256) X[i] = make_float2(sig[i], 0.f);
  __syncthreads();
  fft_core(X, Y, tid, -3.14159265358979323f);
  const float2* H = Hf + ((size_t)k * 512 + c) * HSTR;
  for (int i = tid; i < 4096; i += 256) {
    float2 x = X[i], h;
    if (i <= 2048) h = H[i];
    else { float2 t = H[4096 - i]; h = make_float2(t.x, -t.y); }  // conj symmetry
    X[i] = make_float2(x.x * h.x - x.y * h.y, x.x * h.y + x.y * h.x);
  }
  __syncthreads();
  fft_core(X, Y, tid, 3.14159265358979323f);
  const ushortT* xn = projsT + ((size_t)(k * 4 + b) * 512 + c) * 4096;
  const float scale = 1.0f / 4096.0f;
  for (int i = tid; i < 4096; i += 256)
    sig[i] = X[i].x * scale * bf2f(xn[i]);
}

// ---------------- output GEMM ----------------

__launch_bounds__(256)
__global__ void out_gemm(const float* __restrict__ vT, const float* __restrict__ oW,
                         const float* __restrict__ ob, float* __restrict__ out) {
  int l0 = blockIdx.x * 64;
  int b = l0 >> 12;
  int li = threadIdx.x & 63;
  int og = threadIdx.x >> 6;   // 0..3
  float acc[8] = {};
  const float* vb = vT + (size_t)b * 512 * 4096 + (l0 & 4095) + li;
#pragma unroll 1
  for (int c = 0; c < 512; ++c) {
    float v = vb[(size_t)c * 4096];
#pragma unroll
    for (int j = 0; j < 8; ++j)
      acc[j] = fmaf(v, oW[c * 32 + og * 8 + j], acc[j]);
  }
  float* op = out + (size_t)(l0 + li) * 32 + og * 8;
  f32x4 r0, r1;
  r0[0] = acc[0] + ob[og * 8 + 0]; r0[1] = acc[1] + ob[og * 8 + 1];
  r0[2] = acc[2] + ob[og * 8 + 2]; r0[3] = acc[3] + ob[og * 8 + 3];
  r1[0] = acc[4] + ob[og * 8 + 4]; r1[1] = acc[5] + ob[og * 8 + 5];
  r1[2] = acc[6] + ob[og * 8 + 6]; r1[3] = acc[7] + ob[og * 8 + 7];
  *(f32x4*)op = r0;
  *(f32x4*)(op + 4) = r1;
}

// ---------------- diagnostics ----------------

__global__ void ws_sentinel(float* __restrict__ out) {
  if (threadIdx.x == 0) out[0] = -31337.0f;
}

// ---------------- launch ----------------

extern "C" void kernel_launch(void* const* d_in, const int* in_sizes, int n_in,
                              void* d_out, int out_size, void* d_ws, size_t ws_size,
                              hipStream_t stream) {
  (void)in_sizes; (void)n_in; (void)out_size;
  const float* u  = (const float*)d_in[0];
  const float* pW = (const float*)d_in[1];
  const float* pb = (const float*)d_in[2];
  const float* cW = (const float*)d_in[3];
  const float* cb = (const float*)d_in[4];
  const float* fW = (const float*)d_in[5];
  const float* fb = (const float*)d_in[6];
  const float* oW = (const float*)d_in[7];
  const float* ob = (const float*)d_in[8];
  float* out = (float*)d_out;

  char* ws = (char*)d_ws;
  // persistent region
  ushortT* Apad   = (ushortT*)(ws);                    // 67,141,632  (4x4098x2048 bf16)
  ushortT* Wt     = (ushortT*)(ws + 67141632);         // 25,165,824  (3x2048x2048 bf16)
  float2*  Hf     = (float2*) (ws + 92307456);         // 25,264,128  (1536 x HSTR c64, half-spectrum)
  float*   vT     = (float*)  (ws + 117571584);        // 33,554,432  (4x512x4096 f32)
  ushortT* projsT = (ushortT*)(ws + 151126016);        // 50,331,648  (12x512x4096 bf16)
  const size_t total = 201457664;                      // 192.1 MiB
  // scratch overlay on [vT, end) — all dead before gemm_conv writes vT/projsT
  char* S = (char*)vT;
  ushortT* u_bf   = (ushortT*)(S);                     // 16,777,216
  ushortT* pWt    = (ushortT*)(S + 16777216);          //  2,097,152
  float*   tT     = (float*)  (S + 18874368);          //  2,097,152
  float*   window = (float*)  (S + 20971520);          //     16,384
  float*   hT     = (float*)  (S + 20987904);          // 25,165,824 -> ends 46,153,728 (< 83,886,080)

  if (total > ws_size) {           // diagnostic: distinguishable failure signature
    ws_sentinel<<<1, 64, 0, stream>>>(out);
    return;
  }

  convert_u<<<8192, 256, 0, stream>>>(u, u_bf);
  convert_pW<<<dim3(64, 16), dim3(32, 8), 0, stream>>>(pW, pWt);
  convert_cW<<<16384, 256, 0, stream>>>(cW, Wt);
  zero_pad<<<64, 256, 0, stream>>>(Apad);
  pe_window<<<1024, 256, 0, stream>>>(tT, window);
  gemm_A<<<dim3(128, 16), 256, 0, stream>>>(u_bf, pWt, pb, Apad);       // u_bf,pWt dead after
  h_kernel<<<dim3(64, 12), 256, 0, stream>>>(tT, fW, fb, window, hT);   // tT,window dead after
  fft_filter<<<1536, 256, 0, stream>>>(hT, Hf);                         // hT dead after
  gemm_conv<<<dim3(128, 16), 256, 0, stream>>>(Apad, Wt, cb, vT, projsT);
  for (int k = 0; k < 3; ++k)
    fft_conv<<<2048, 256, 0, stream>>>(vT, projsT, Hf, k);
  out_gemm<<<256, 256, 0, stream>>>(vT, oW, ob, out);
}

// Round 4
// 962.769 us; speedup vs baseline: 3.9864x; 1.1051x over previous
//
#include <hip/hip_runtime.h>

typedef __attribute__((ext_vector_type(8))) short short8;
typedef __attribute__((ext_vector_type(4))) float f32x4;
typedef __attribute__((ext_vector_type(4))) unsigned short ushort4v;
typedef unsigned short ushortT;

#define PADROWS 4098
#define HSTR 2056   // half-spectrum row stride (float2), 64B-aligned

__device__ __forceinline__ ushortT f2bf(float f) {
  union { float f; unsigned int u; } v; v.f = f;
  unsigned int r = (v.u + 0x7FFFu + ((v.u >> 16) & 1u)) >> 16;
  return (ushortT)r;
}
__device__ __forceinline__ float bf2f(ushortT b) {
  union { unsigned int u; float f; } v; v.u = ((unsigned int)b) << 16;
  return v.f;
}

__device__ __forceinline__ void gl2lds16(const void* g, void* l) {
  __builtin_amdgcn_global_load_lds((const __attribute__((address_space(1))) void*)g,
                                   (__attribute__((address_space(3))) void*)l, 16, 0, 0);
}

// ---------------- conversions ----------------

__global__ void convert_u(const float* __restrict__ in, ushortT* __restrict__ outb) {
  size_t idx = (size_t)blockIdx.x * 256 + threadIdx.x;  // one per 4 elems
  f32x4 v = *(const f32x4*)(in + idx * 4);
  ushort4v r;
  r[0] = f2bf(v[0]); r[1] = f2bf(v[1]); r[2] = f2bf(v[2]); r[3] = f2bf(v[3]);
  *(ushort4v*)(outb + idx * 4) = r;
}

// pW (512,2048) f32 -> pWt (2048,512) bf16
__global__ void convert_pW(const float* __restrict__ pW, ushortT* __restrict__ pWt) {
  __shared__ float tile[32][33];
  int rt = blockIdx.y * 32;   // row in pW (i)
  int ct = blockIdx.x * 32;   // col in pW (o)
  int tx = threadIdx.x, ty = threadIdx.y;
#pragma unroll
  for (int q = 0; q < 32; q += 8)
    tile[ty + q][tx] = pW[(size_t)(rt + ty + q) * 2048 + ct + tx];
  __syncthreads();
#pragma unroll
  for (int q = 0; q < 32; q += 8)
    pWt[(size_t)(ct + ty + q) * 512 + rt + tx] = f2bf(tile[tx][ty + q]);
}

// cW (2048,2048,3) f32 -> Wt[h][o][i] bf16
__global__ void convert_cW(const float* __restrict__ cW, ushortT* __restrict__ Wt) {
  size_t idx = (size_t)blockIdx.x * 256 + threadIdx.x;  // (o,i)
  const float* p = cW + idx * 3;
  float w0 = p[0], w1 = p[1], w2 = p[2];
  Wt[idx]           = f2bf(w0);
  Wt[idx + 4194304] = f2bf(w1);
  Wt[idx + 8388608] = f2bf(w2);
}

__global__ void zero_pad(ushortT* __restrict__ Apad) {
  int idx = blockIdx.x * 256 + threadIdx.x;   // 16384 = 4b * 2r * 2048i
  int i = idx & 2047;
  int r = (idx >> 11) & 1;
  int b = idx >> 12;
  Apad[((size_t)b * PADROWS + (r ? 4097 : 0)) * 2048 + i] = 0;
}

// tT[128][4096], window[4096]
__global__ void pe_window(float* __restrict__ tT, float* __restrict__ window) {
  int idx = blockIdx.x * 256 + threadIdx.x;  // 262144
  int l = idx & 4095, d2 = idx >> 12;        // d2 in 0..63
  float dv = expf(-9.210340371976184f * (float)(2 * d2) / 128.0f);
  float ang = (float)l * dv;
  tT[(size_t)(2 * d2) * 4096 + l] = sinf(ang);
  tT[(size_t)(2 * d2 + 1) * 4096 + l] = cosf(ang);
  if (d2 == 0)
    window[l] = 0.5f * (1.0f - cosf(6.283185307179586f * (float)l / 4095.0f));
}

// ---------------- GEMM 1: hat_z = u @ pW + pb -> Apad (padded, bf16) ----------------

__launch_bounds__(256, 2)
__global__ void gemm_A(const ushortT* __restrict__ u_bf, const ushortT* __restrict__ pWt,
                       const float* __restrict__ pb, ushortT* __restrict__ Apad) {
  __shared__ alignas(16) ushortT As[128 * 64];
  __shared__ alignas(16) ushortT Bs[128 * 64];
  const int tid = threadIdx.x;
  const int lane = tid & 63, w = tid >> 6;
  const int wm = w >> 1, wn = w & 1;
  const int tm = blockIdx.x, tn = blockIdx.y;
  f32x4 acc[4][4] = {};
#pragma unroll 1
  for (int kt = 0; kt < 8; ++kt) {
    const int i0 = kt * 64;
#pragma unroll
    for (int i = 0; i < 4; ++i) {
      int ldsoff = (i * 4 + w) * 1024;            // bytes, wave-uniform
      int m = ((i * 4 + w) << 3) + (lane >> 3);   // tile row 0..127
      int col = (lane & 7) * 8;                   // k-offset (bf16 elems), linear
      gl2lds16(u_bf + (size_t)(tm * 128 + m) * 512 + i0 + col, (char*)As + ldsoff);
      gl2lds16(pWt  + (size_t)(tn * 128 + m) * 512 + i0 + col, (char*)Bs + ldsoff);
    }
    __syncthreads();
#pragma unroll
    for (int ks = 0; ks < 2; ++ks) {
      short8 av[4], bv[4];
#pragma unroll
      for (int mi = 0; mi < 4; ++mi) {
        int row = wm * 64 + mi * 16 + (lane & 15);
        av[mi] = *(const short8*)(As + row * 64 + (ks * 4 + (lane >> 4)) * 8);
      }
#pragma unroll
      for (int ni = 0; ni < 4; ++ni) {
        int row = wn * 64 + ni * 16 + (lane & 15);
        bv[ni] = *(const short8*)(Bs + row * 64 + (ks * 4 + (lane >> 4)) * 8);
      }
#pragma unroll
      for (int mi = 0; mi < 4; ++mi)
#pragma unroll
        for (int ni = 0; ni < 4; ++ni)
          acc[mi][ni] = __builtin_amdgcn_mfma_f32_16x16x32_bf16(av[mi], bv[ni], acc[mi][ni], 0, 0, 0);
    }
    __syncthreads();
  }
#pragma unroll
  for (int mi = 0; mi < 4; ++mi)
#pragma unroll
    for (int ni = 0; ni < 4; ++ni) {
      int gc = tn * 128 + wn * 64 + ni * 16 + (lane & 15);
      float bias = pb[gc];
#pragma unroll
      for (int j = 0; j < 4; ++j) {
        int gl = tm * 128 + wm * 64 + mi * 16 + (lane >> 4) * 4 + j;
        int b = gl >> 12;
        Apad[((size_t)b * PADROWS + (gl & 4095) + 1) * 2048 + gc] = f2bf(acc[mi][ni][j] + bias);
      }
    }
}

// ---------------- GEMM 2: 3-tap conv, 256x256 8-phase pipeline, transposed output ----------------
// M-side = o (2048, via Wt rows), N-side = l (16384, via Apad rows). C[o][l] -> vT/projsT direct.
// 8 waves (2 wm x 4 wn), per-wave 128(o) x 64(l). LDS: 2 K-step slots x (W 32K + X 32K) = 128 KiB.
// Swizzle: LDS 16B-chunk c of row r holds global chunk c ^ (r&7); linear gl2lds dest + pre-swizzled
// global source; ds_read applies same XOR (involution, rule #21).

__launch_bounds__(512, 2)
__global__ void gemm_conv8(const ushortT* __restrict__ Apad, const ushortT* __restrict__ Wt,
                           const float* __restrict__ cb, float* __restrict__ vT,
                           ushortT* __restrict__ projsT) {
  __shared__ ushortT lds[2][2][16384];  // [slot][0=W,1=X][256 rows x 64 bf16]
  const int tid = threadIdx.x;
  const int lane = tid & 63, w = tid >> 6;   // 8 waves
  const int wm = w >> 2, wn = w & 3;         // 2 x 4
  int raw = blockIdx.x;                       // 512 wgs
  int wg  = (raw & 7) * 64 + (raw >> 3);      // bijective XCD chunking (512 % 8 == 0)
  const int o0 = (wg >> 6) << 8;              // o tile 0..7
  const int nt = wg & 63;
  const int b  = nt >> 4;
  const int l0 = (nt & 15) << 8;

  f32x4 acc[8][4] = {};
  short8 xf[4][2];

  const int sm = tid >> 3;                    // staging row 0..63 (and +64)
  const int sw1 = ((tid & 7) ^ (sm & 7)) << 3;  // pre-swizzled source chunk (elements)

  auto stageW = [&](int slot, int half, int t) {
    int h = t >> 5, i0 = (t & 31) << 6;
    size_t grow = (size_t)(h * 2048 + o0 + half * 128 + sm);
    char* dst = (char*)&lds[slot][0][0] + half * 16384 + w * 1024;
    gl2lds16(Wt + grow * 2048 + i0 + sw1, dst);
    gl2lds16(Wt + (grow + 64) * 2048 + i0 + sw1, dst + 8192);
  };
  auto stageX = [&](int slot, int half, int t) {
    int h = t >> 5, i0 = (t & 31) << 6;
    size_t grow = (size_t)b * PADROWS + l0 + h + half * 128 + sm;
    char* dst = (char*)&lds[slot][1][0] + half * 16384 + w * 1024;
    gl2lds16(Apad + grow * 2048 + i0 + sw1, dst);
    gl2lds16(Apad + (grow + 64) * 2048 + i0 + sw1, dst + 8192);
  };
  auto ldsW = [&](int slot, int mi, int ks) -> short8 {
    int row = wm * 128 + mi * 16 + (lane & 15);
    int ch = (ks * 4 + (lane >> 4)) ^ (row & 7);
    return *(const short8*)&lds[slot][0][row * 64 + ch * 8];
  };
  auto ldsX = [&](int slot, int ni, int ks) -> short8 {
    int row = wn * 64 + ni * 16 + (lane & 15);
    int ch = (ks * 4 + (lane >> 4)) ^ (row & 7);
    return *(const short8*)&lds[slot][1][row * 64 + ch * 8];
  };

  // prologue: step0 W+X -> slot0; step1 X -> slot1 (step1 W staged in-loop ph0/ph1)
  stageW(0, 0, 0); stageW(0, 1, 0);
  stageX(0, 0, 0); stageX(0, 1, 0);
  stageX(1, 0, 1); stageX(1, 1, 1);
  asm volatile("s_waitcnt vmcnt(0)" ::: "memory");
  __builtin_amdgcn_s_barrier();

#define PHASE(slot, q, STAGECODE, VMCODE)                                                                    \
  {                                                                                                          \
    short8 w0k0 = ldsW(slot, 2*(q), 0), w0k1 = ldsW(slot, 2*(q), 1);                                         \
    short8 w1k0 = ldsW(slot, 2*(q)+1, 0), w1k1 = ldsW(slot, 2*(q)+1, 1);                                     \
    if ((q) == 0) {                                                                                          \
      _Pragma("unroll")                                                                                      \
      for (int ni = 0; ni < 4; ++ni) {                                                                       \
        xf[ni][0] = ldsX(slot, ni, 0);                                                                       \
        xf[ni][1] = ldsX(slot, ni, 1);                                                                       \
      }                                                                                                      \
    }                                                                                                        \
    STAGECODE;                                                                                               \
    VMCODE;                                                                                                  \
    __builtin_amdgcn_s_barrier();                                                                            \
    asm volatile("s_waitcnt lgkmcnt(0)" ::: "memory");                                                       \
    __builtin_amdgcn_sched_barrier(0);                                                                       \
    __builtin_amdgcn_s_setprio(1);                                                                           \
    _Pragma("unroll")                                                                                        \
    for (int ni = 0; ni < 4; ++ni) {                                                                         \
      acc[2*(q)][ni]   = __builtin_amdgcn_mfma_f32_16x16x32_bf16(w0k0, xf[ni][0], acc[2*(q)][ni], 0, 0, 0);  \
      acc[2*(q)][ni]   = __builtin_amdgcn_mfma_f32_16x16x32_bf16(w0k1, xf[ni][1], acc[2*(q)][ni], 0, 0, 0);  \
      acc[2*(q)+1][ni] = __builtin_amdgcn_mfma_f32_16x16x32_bf16(w1k0, xf[ni][0], acc[2*(q)+1][ni], 0, 0, 0);\
      acc[2*(q)+1][ni] = __builtin_amdgcn_mfma_f32_16x16x32_bf16(w1k1, xf[ni][1], acc[2*(q)+1][ni], 0, 0, 0);\
    }                                                                                                        \
    __builtin_amdgcn_s_setprio(0);                                                                           \
    __builtin_amdgcn_s_barrier();                                                                            \
  }

#pragma unroll 1
  for (int it = 0; it < 47; ++it) {
    const int t0 = 2 * it;
    PHASE(0, 0, stageW(1, 0, t0 + 1), );
    PHASE(0, 1, stageW(1, 1, t0 + 1), );
    PHASE(0, 2, stageX(0, 0, t0 + 2), );
    PHASE(0, 3, stageX(0, 1, t0 + 2), asm volatile("s_waitcnt vmcnt(4)" ::: "memory"));
    PHASE(1, 0, stageW(0, 0, t0 + 2), );
    PHASE(1, 1, stageW(0, 1, t0 + 2), );
    PHASE(1, 2, stageX(1, 0, t0 + 3), );
    PHASE(1, 3, stageX(1, 1, t0 + 3), asm volatile("s_waitcnt vmcnt(4)" ::: "memory"));
  }
  // peeled last iteration: steps 94 (slot0), 95 (slot1); only step95's W still needs staging
  PHASE(0, 0, stageW(1, 0, 95), );
  PHASE(0, 1, stageW(1, 1, 95), );
  PHASE(0, 2, , );
  PHASE(0, 3, , asm volatile("s_waitcnt vmcnt(0)" ::: "memory"));
  PHASE(1, 0, , );
  PHASE(1, 1, , );
  PHASE(1, 2, , );
  PHASE(1, 3, , );
#undef PHASE

  // epilogue: D row = o, col = l
  const int r4 = (lane >> 4) * 4;
  const int lbase = l0 + wn * 64 + (lane & 15);
  if (o0 < 512) {
#pragma unroll
    for (int mi = 0; mi < 8; ++mi)
#pragma unroll
      for (int ni = 0; ni < 4; ++ni) {
        int l = lbase + ni * 16;
#pragma unroll
        for (int j = 0; j < 4; ++j) {
          int o = o0 + wm * 128 + mi * 16 + r4 + j;
          vT[((size_t)b * 512 + o) * 4096 + l] = acc[mi][ni][j] + cb[o];
        }
      }
  } else {
#pragma unroll
    for (int mi = 0; mi < 8; ++mi)
#pragma unroll
      for (int ni = 0; ni < 4; ++ni) {
        int l = lbase + ni * 16;
#pragma unroll
        for (int j = 0; j < 4; ++j) {
          int o = o0 + wm * 128 + mi * 16 + r4 + j;
          int oc = o - 512;
          projsT[((size_t)((oc >> 9) * 4 + b) * 512 + (oc & 511)) * 4096 + l] = f2bf(acc[mi][ni][j] + cb[o]);
        }
      }
  }
}

// ---------------- filter GEMM: hT[ch][l] = (t @ fW + fb)*window, f32, LDS-tiled ----------------
// grid (64, 12): l-tile 64, ch-tile 128. 96 KiB LDS. 4l x 8ch register block/thread.

__launch_bounds__(256, 1)
__global__ void h_kernel(const float* __restrict__ tT, const float* __restrict__ fW,
                         const float* __restrict__ fb, const float* __restrict__ window,
                         float* __restrict__ hT) {
  __shared__ float tTs[128][64];    // 32 KiB  [d][l]
  __shared__ float fWs[128][128];   // 64 KiB  [d][ch]
  const int l0 = blockIdx.x * 64;
  const int c0 = blockIdx.y * 128;
  const int tid = threadIdx.x;
  {
    int lq = (tid & 15) * 4;     // l offset in tile
    int dr = tid >> 4;           // 0..15
#pragma unroll
    for (int d = dr; d < 128; d += 16)
      *(f32x4*)(&tTs[d][lq]) = *(const f32x4*)(tT + (size_t)d * 4096 + l0 + lq);
  }
  {
    int cq = (tid & 31) * 4;     // ch offset in tile
    int dr = tid >> 5;           // 0..7
#pragma unroll
    for (int d = dr; d < 128; d += 8)
      *(f32x4*)(&fWs[d][cq]) = *(const f32x4*)(fW + (size_t)d * 1536 + c0 + cq);
  }
  __syncthreads();
  const int lgrp = tid & 15;     // 4 l's each
  const int cg = tid >> 4;       // 0..15, 8 ch each strided 16 (conflict-free)
  float acc[8][4] = {};
#pragma unroll 4
  for (int d = 0; d < 128; ++d) {
    f32x4 tv = *(const f32x4*)(&tTs[d][lgrp * 4]);
#pragma unroll
    for (int j = 0; j < 8; ++j) {
      float wv = fWs[d][cg + 16 * j];
      acc[j][0] = fmaf(tv[0], wv, acc[j][0]);
      acc[j][1] = fmaf(tv[1], wv, acc[j][1]);
      acc[j][2] = fmaf(tv[2], wv, acc[j][2]);
      acc[j][3] = fmaf(tv[3], wv, acc[j][3]);
    }
  }
  f32x4 wl = *(const f32x4*)(window + l0 + lgrp * 4);
#pragma unroll
  for (int j = 0; j < 8; ++j) {
    int ch = c0 + cg + 16 * j;
    float fbv = fb[ch];
    f32x4 r;
    r[0] = (acc[j][0] + fbv) * wl[0];
    r[1] = (acc[j][1] + fbv) * wl[1];
    r[2] = (acc[j][2] + fbv) * wl[2];
    r[3] = (acc[j][3] + fbv) * wl[3];
    *(f32x4*)(hT + (size_t)ch * 4096 + l0 + lgrp * 4) = r;
  }
}

// ---------------- FFT (Stockham radix-2, N=4096, complex) ----------------

__device__ void fft_core(float2* sA, float2* sB, int tid, float dirpi) {
  float2* src = sA;
  float2* dst = sB;
#pragma unroll 1
  for (int s = 0; s < 12; ++s) {
    const int m = 1 << s;
    const int lh = 2048 >> s;
    const float w0 = dirpi / (float)lh;
#pragma unroll
    for (int p = tid; p < 2048; p += 256) {
      int j = p >> s;
      int jm = p & ~(m - 1);
      float2 a = src[p];
      float2 c = src[p + 2048];
      float sn, cs;
      __sincosf(w0 * (float)j, &sn, &cs);
      float dx = a.x - c.x, dy = a.y - c.y;
      dst[p + jm] = make_float2(a.x + c.x, a.y + c.y);
      dst[p + jm + m] = make_float2(dx * cs - dy * sn, dx * sn + dy * cs);
    }
    __syncthreads();
    float2* t = src; src = dst; dst = t;
  }
}

__launch_bounds__(256, 1)
__global__ void fft_filter(const float* __restrict__ hT, float2* __restrict__ Hf) {
  __shared__ float2 X[4096];
  __shared__ float2 Y[4096];
  int ch = blockIdx.x;
  const float* sig = hT + (size_t)ch * 4096;
  for (int i = threadIdx.x; i < 4096; i += 256) X[i] = make_float2(sig[i], 0.f);
  __syncthreads();
  fft_core(X, Y, threadIdx.x, -3.14159265358979323f);
  float2* o = Hf + (size_t)ch * HSTR;
  for (int i = threadIdx.x; i <= 2048; i += 256) o[i] = X[i];   // half spectrum
}

__launch_bounds__(256, 1)
__global__ void fft_conv(float* __restrict__ vT, const ushortT* __restrict__ projsT,
                         const float2* __restrict__ Hf, int k) {
  __shared__ float2 X[4096];
  __shared__ float2 Y[4096];
  int bc = blockIdx.x;   // b*512 + c
  int c = bc & 511, b = bc >> 9;
  int tid = threadIdx.x;
  float* sig = vT + (size_t)bc * 4096;
  for (int i = tid; i < 4096; i += 256) X[i] = make_float2(sig[i], 0.f);
  __syncthreads();
  fft_core(X, Y, tid, -3.14159265358979323f);
  const float2* H = Hf + ((size_t)k * 512 + c) * HSTR;
  for (int i = tid; i < 4096; i += 256) {
    float2 x = X[i], h;
    if (i <= 2048) h = H[i];
    else { float2 t = H[4096 - i]; h = make_float2(t.x, -t.y); }  // conj symmetry
    X[i] = make_float2(x.x * h.x - x.y * h.y, x.x * h.y + x.y * h.x);
  }
  __syncthreads();
  fft_core(X, Y, tid, 3.14159265358979323f);
  const ushortT* xn = projsT + ((size_t)(k * 4 + b) * 512 + c) * 4096;
  const float scale = 1.0f / 4096.0f;
  for (int i = tid; i < 4096; i += 256)
    sig[i] = X[i].x * scale * bf2f(xn[i]);
}

// ---------------- output GEMM ----------------

__launch_bounds__(256)
__global__ void out_gemm(const float* __restrict__ vT, const float* __restrict__ oW,
                         const float* __restrict__ ob, float* __restrict__ out) {
  int l0 = blockIdx.x * 64;
  int b = l0 >> 12;
  int li = threadIdx.x & 63;
  int og = threadIdx.x >> 6;   // 0..3
  float acc[8] = {};
  const float* vb = vT + (size_t)b * 512 * 4096 + (l0 & 4095) + li;
#pragma unroll 1
  for (int c = 0; c < 512; ++c) {
    float v = vb[(size_t)c * 4096];
#pragma unroll
    for (int j = 0; j < 8; ++j)
      acc[j] = fmaf(v, oW[c * 32 + og * 8 + j], acc[j]);
  }
  float* op = out + (size_t)(l0 + li) * 32 + og * 8;
  f32x4 r0, r1;
  r0[0] = acc[0] + ob[og * 8 + 0]; r0[1] = acc[1] + ob[og * 8 + 1];
  r0[2] = acc[2] + ob[og * 8 + 2]; r0[3] = acc[3] + ob[og * 8 + 3];
  r1[0] = acc[4] + ob[og * 8 + 4]; r1[1] = acc[5] + ob[og * 8 + 5];
  r1[2] = acc[6] + ob[og * 8 + 6]; r1[3] = acc[7] + ob[og * 8 + 7];
  *(f32x4*)op = r0;
  *(f32x4*)(op + 4) = r1;
}

// ---------------- diagnostics ----------------

__global__ void ws_sentinel(float* __restrict__ out) {
  if (threadIdx.x == 0) out[0] = -31337.0f;
}

// ---------------- launch ----------------

extern "C" void kernel_launch(void* const* d_in, const int* in_sizes, int n_in,
                              void* d_out, int out_size, void* d_ws, size_t ws_size,
                              hipStream_t stream) {
  (void)in_sizes; (void)n_in; (void)out_size;
  const float* u  = (const float*)d_in[0];
  const float* pW = (const float*)d_in[1];
  const float* pb = (const float*)d_in[2];
  const float* cW = (const float*)d_in[3];
  const float* cb = (const float*)d_in[4];
  const float* fW = (const float*)d_in[5];
  const float* fb = (const float*)d_in[6];
  const float* oW = (const float*)d_in[7];
  const float* ob = (const float*)d_in[8];
  float* out = (float*)d_out;

  char* ws = (char*)d_ws;
  // persistent region
  ushortT* Apad   = (ushortT*)(ws);                    // 67,141,632  (4x4098x2048 bf16)
  ushortT* Wt     = (ushortT*)(ws + 67141632);         // 25,165,824  (3x2048x2048 bf16)
  float2*  Hf     = (float2*) (ws + 92307456);         // 25,264,128  (1536 x HSTR c64, half-spectrum)
  float*   vT     = (float*)  (ws + 117571584);        // 33,554,432  (4x512x4096 f32)
  ushortT* projsT = (ushortT*)(ws + 151126016);        // 50,331,648  (12x512x4096 bf16)
  const size_t total = 201457664;                      // 192.1 MiB
  // scratch overlay on [vT, end) — all dead before gemm_conv8 writes vT/projsT
  char* S = (char*)vT;
  ushortT* u_bf   = (ushortT*)(S);                     // 16,777,216
  ushortT* pWt    = (ushortT*)(S + 16777216);          //  2,097,152
  float*   tT     = (float*)  (S + 18874368);          //  2,097,152
  float*   window = (float*)  (S + 20971520);          //     16,384
  float*   hT     = (float*)  (S + 20987904);          // 25,165,824 -> ends 46,153,728 (< 83,886,080)

  if (total > ws_size) {           // diagnostic: distinguishable failure signature
    ws_sentinel<<<1, 64, 0, stream>>>(out);
    return;
  }

  convert_u<<<8192, 256, 0, stream>>>(u, u_bf);
  convert_pW<<<dim3(64, 16), dim3(32, 8), 0, stream>>>(pW, pWt);
  convert_cW<<<16384, 256, 0, stream>>>(cW, Wt);
  zero_pad<<<64, 256, 0, stream>>>(Apad);
  pe_window<<<1024, 256, 0, stream>>>(tT, window);
  gemm_A<<<dim3(128, 16), 256, 0, stream>>>(u_bf, pWt, pb, Apad);       // u_bf,pWt dead after
  h_kernel<<<dim3(64, 12), 256, 0, stream>>>(tT, fW, fb, window, hT);   // tT,window dead after
  fft_filter<<<1536, 256, 0, stream>>>(hT, Hf);                         // hT dead after
  gemm_conv8<<<512, 512, 0, stream>>>(Apad, Wt, cb, vT, projsT);
  for (int k = 0; k < 3; ++k)
    fft_conv<<<2048, 256, 0, stream>>>(vT, projsT, Hf, k);
  out_gemm<<<256, 256, 0, stream>>>(vT, oW, ob, out);
}

// Round 5
// 674.157 us; speedup vs baseline: 5.6931x; 1.4281x over previous
//
#include <hip/hip_runtime.h>

typedef __attribute__((ext_vector_type(8))) short short8;
typedef __attribute__((ext_vector_type(4))) float f32x4;
typedef __attribute__((ext_vector_type(4))) unsigned short ushort4v;
typedef unsigned short ushortT;

#define PADROWS 4098
#define HSTR 2056   // half-spectrum row stride (float2), 64B-aligned
#define PI_F 3.14159265358979323f

__device__ __forceinline__ ushortT f2bf(float f) {
  union { float f; unsigned int u; } v; v.f = f;
  unsigned int r = (v.u + 0x7FFFu + ((v.u >> 16) & 1u)) >> 16;
  return (ushortT)r;
}
__device__ __forceinline__ float bf2f(ushortT b) {
  union { unsigned int u; float f; } v; v.u = ((unsigned int)b) << 16;
  return v.f;
}

__device__ __forceinline__ void gl2lds16(const void* g, void* l) {
  __builtin_amdgcn_global_load_lds((const __attribute__((address_space(1))) void*)g,
                                   (__attribute__((address_space(3))) void*)l, 16, 0, 0);
}

// ---------------- conversions ----------------

__global__ void convert_u(const float* __restrict__ in, ushortT* __restrict__ outb) {
  size_t idx = (size_t)blockIdx.x * 256 + threadIdx.x;  // one per 4 elems
  f32x4 v = *(const f32x4*)(in + idx * 4);
  ushort4v r;
  r[0] = f2bf(v[0]); r[1] = f2bf(v[1]); r[2] = f2bf(v[2]); r[3] = f2bf(v[3]);
  *(ushort4v*)(outb + idx * 4) = r;
}

// pW (512,2048) f32 -> pWt (2048,512) bf16
__global__ void convert_pW(const float* __restrict__ pW, ushortT* __restrict__ pWt) {
  __shared__ float tile[32][33];
  int rt = blockIdx.y * 32;   // row in pW (i)
  int ct = blockIdx.x * 32;   // col in pW (o)
  int tx = threadIdx.x, ty = threadIdx.y;
#pragma unroll
  for (int q = 0; q < 32; q += 8)
    tile[ty + q][tx] = pW[(size_t)(rt + ty + q) * 2048 + ct + tx];
  __syncthreads();
#pragma unroll
  for (int q = 0; q < 32; q += 8)
    pWt[(size_t)(ct + ty + q) * 512 + rt + tx] = f2bf(tile[tx][ty + q]);
}

// cW (2048,2048,3) f32 -> Wt[h][o][i] bf16
__global__ void convert_cW(const float* __restrict__ cW, ushortT* __restrict__ Wt) {
  size_t idx = (size_t)blockIdx.x * 256 + threadIdx.x;  // (o,i)
  const float* p = cW + idx * 3;
  float w0 = p[0], w1 = p[1], w2 = p[2];
  Wt[idx]           = f2bf(w0);
  Wt[idx + 4194304] = f2bf(w1);
  Wt[idx + 8388608] = f2bf(w2);
}

__global__ void zero_pad(ushortT* __restrict__ Apad) {
  int idx = blockIdx.x * 256 + threadIdx.x;   // 16384 = 4b * 2r * 2048i
  int i = idx & 2047;
  int r = (idx >> 11) & 1;
  int b = idx >> 12;
  Apad[((size_t)b * PADROWS + (r ? 4097 : 0)) * 2048 + i] = 0;
}

// tT[128][4096], window[4096]
__global__ void pe_window(float* __restrict__ tT, float* __restrict__ window) {
  int idx = blockIdx.x * 256 + threadIdx.x;  // 262144
  int l = idx & 4095, d2 = idx >> 12;        // d2 in 0..63
  float dv = expf(-9.210340371976184f * (float)(2 * d2) / 128.0f);
  float ang = (float)l * dv;
  tT[(size_t)(2 * d2) * 4096 + l] = sinf(ang);
  tT[(size_t)(2 * d2 + 1) * 4096 + l] = cosf(ang);
  if (d2 == 0)
    window[l] = 0.5f * (1.0f - cosf(6.283185307179586f * (float)l / 4095.0f));
}

// ---------------- GEMM 1: hat_z = u @ pW + pb -> Apad (padded, bf16) ----------------

__launch_bounds__(256, 2)
__global__ void gemm_A(const ushortT* __restrict__ u_bf, const ushortT* __restrict__ pWt,
                       const float* __restrict__ pb, ushortT* __restrict__ Apad) {
  __shared__ alignas(16) ushortT As[128 * 64];
  __shared__ alignas(16) ushortT Bs[128 * 64];
  const int tid = threadIdx.x;
  const int lane = tid & 63, w = tid >> 6;
  const int wm = w >> 1, wn = w & 1;
  const int tm = blockIdx.x, tn = blockIdx.y;
  f32x4 acc[4][4] = {};
#pragma unroll 1
  for (int kt = 0; kt < 8; ++kt) {
    const int i0 = kt * 64;
#pragma unroll
    for (int i = 0; i < 4; ++i) {
      int ldsoff = (i * 4 + w) * 1024;            // bytes, wave-uniform
      int m = ((i * 4 + w) << 3) + (lane >> 3);   // tile row 0..127
      int col = (lane & 7) * 8;                   // k-offset (bf16 elems), linear
      gl2lds16(u_bf + (size_t)(tm * 128 + m) * 512 + i0 + col, (char*)As + ldsoff);
      gl2lds16(pWt  + (size_t)(tn * 128 + m) * 512 + i0 + col, (char*)Bs + ldsoff);
    }
    __syncthreads();
#pragma unroll
    for (int ks = 0; ks < 2; ++ks) {
      short8 av[4], bv[4];
#pragma unroll
      for (int mi = 0; mi < 4; ++mi) {
        int row = wm * 64 + mi * 16 + (lane & 15);
        av[mi] = *(const short8*)(As + row * 64 + (ks * 4 + (lane >> 4)) * 8);
      }
#pragma unroll
      for (int ni = 0; ni < 4; ++ni) {
        int row = wn * 64 + ni * 16 + (lane & 15);
        bv[ni] = *(const short8*)(Bs + row * 64 + (ks * 4 + (lane >> 4)) * 8);
      }
#pragma unroll
      for (int mi = 0; mi < 4; ++mi)
#pragma unroll
        for (int ni = 0; ni < 4; ++ni)
          acc[mi][ni] = __builtin_amdgcn_mfma_f32_16x16x32_bf16(av[mi], bv[ni], acc[mi][ni], 0, 0, 0);
    }
    __syncthreads();
  }
#pragma unroll
  for (int mi = 0; mi < 4; ++mi)
#pragma unroll
    for (int ni = 0; ni < 4; ++ni) {
      int gc = tn * 128 + wn * 64 + ni * 16 + (lane & 15);
      float bias = pb[gc];
#pragma unroll
      for (int j = 0; j < 4; ++j) {
        int gl = tm * 128 + wm * 64 + mi * 16 + (lane >> 4) * 4 + j;
        int b = gl >> 12;
        Apad[((size_t)b * PADROWS + (gl & 4095) + 1) * 2048 + gc] = f2bf(acc[mi][ni][j] + bias);
      }
    }
}

// ---------------- GEMM 2: 3-tap conv, 256x256 8-phase pipeline, transposed output ----------------

__launch_bounds__(512, 2)
__global__ void gemm_conv8(const ushortT* __restrict__ Apad, const ushortT* __restrict__ Wt,
                           const float* __restrict__ cb, float* __restrict__ vT,
                           ushortT* __restrict__ projsT) {
  __shared__ ushortT lds[2][2][16384];  // [slot][0=W,1=X][256 rows x 64 bf16]
  const int tid = threadIdx.x;
  const int lane = tid & 63, w = tid >> 6;   // 8 waves
  const int wm = w >> 2, wn = w & 3;         // 2 x 4
  int raw = blockIdx.x;                       // 512 wgs
  int wg  = (raw & 7) * 64 + (raw >> 3);      // bijective XCD chunking (512 % 8 == 0)
  const int o0 = (wg >> 6) << 8;              // o tile 0..7
  const int nt = wg & 63;
  const int b  = nt >> 4;
  const int l0 = (nt & 15) << 8;

  f32x4 acc[8][4] = {};
  short8 xf[4][2];

  const int sm = tid >> 3;                    // staging row 0..63 (and +64)
  const int sw1 = ((tid & 7) ^ (sm & 7)) << 3;  // pre-swizzled source chunk (elements)

  auto stageW = [&](int slot, int half, int t) {
    int h = t >> 5, i0 = (t & 31) << 6;
    size_t grow = (size_t)(h * 2048 + o0 + half * 128 + sm);
    char* dst = (char*)&lds[slot][0][0] + half * 16384 + w * 1024;
    gl2lds16(Wt + grow * 2048 + i0 + sw1, dst);
    gl2lds16(Wt + (grow + 64) * 2048 + i0 + sw1, dst + 8192);
  };
  auto stageX = [&](int slot, int half, int t) {
    int h = t >> 5, i0 = (t & 31) << 6;
    size_t grow = (size_t)b * PADROWS + l0 + h + half * 128 + sm;
    char* dst = (char*)&lds[slot][1][0] + half * 16384 + w * 1024;
    gl2lds16(Apad + grow * 2048 + i0 + sw1, dst);
    gl2lds16(Apad + (grow + 64) * 2048 + i0 + sw1, dst + 8192);
  };
  auto ldsW = [&](int slot, int mi, int ks) -> short8 {
    int row = wm * 128 + mi * 16 + (lane & 15);
    int ch = (ks * 4 + (lane >> 4)) ^ (row & 7);
    return *(const short8*)&lds[slot][0][row * 64 + ch * 8];
  };
  auto ldsX = [&](int slot, int ni, int ks) -> short8 {
    int row = wn * 64 + ni * 16 + (lane & 15);
    int ch = (ks * 4 + (lane >> 4)) ^ (row & 7);
    return *(const short8*)&lds[slot][1][row * 64 + ch * 8];
  };

  // prologue: step0 W+X -> slot0; step1 X -> slot1 (step1 W staged in-loop ph0/ph1)
  stageW(0, 0, 0); stageW(0, 1, 0);
  stageX(0, 0, 0); stageX(0, 1, 0);
  stageX(1, 0, 1); stageX(1, 1, 1);
  asm volatile("s_waitcnt vmcnt(0)" ::: "memory");
  __builtin_amdgcn_s_barrier();

#define PHASE(slot, q, STAGECODE, VMCODE)                                                                    \
  {                                                                                                          \
    short8 w0k0 = ldsW(slot, 2*(q), 0), w0k1 = ldsW(slot, 2*(q), 1);                                         \
    short8 w1k0 = ldsW(slot, 2*(q)+1, 0), w1k1 = ldsW(slot, 2*(q)+1, 1);                                     \
    if ((q) == 0) {                                                                                          \
      _Pragma("unroll")                                                                                      \
      for (int ni = 0; ni < 4; ++ni) {                                                                       \
        xf[ni][0] = ldsX(slot, ni, 0);                                                                       \
        xf[ni][1] = ldsX(slot, ni, 1);                                                                       \
      }                                                                                                      \
    }                                                                                                        \
    STAGECODE;                                                                                               \
    VMCODE;                                                                                                  \
    __builtin_amdgcn_s_barrier();                                                                            \
    asm volatile("s_waitcnt lgkmcnt(0)" ::: "memory");                                                       \
    __builtin_amdgcn_sched_barrier(0);                                                                       \
    __builtin_amdgcn_s_setprio(1);                                                                           \
    _Pragma("unroll")                                                                                        \
    for (int ni = 0; ni < 4; ++ni) {                                                                         \
      acc[2*(q)][ni]   = __builtin_amdgcn_mfma_f32_16x16x32_bf16(w0k0, xf[ni][0], acc[2*(q)][ni], 0, 0, 0);  \
      acc[2*(q)][ni]   = __builtin_amdgcn_mfma_f32_16x16x32_bf16(w0k1, xf[ni][1], acc[2*(q)][ni], 0, 0, 0);  \
      acc[2*(q)+1][ni] = __builtin_amdgcn_mfma_f32_16x16x32_bf16(w1k0, xf[ni][0], acc[2*(q)+1][ni], 0, 0, 0);\
      acc[2*(q)+1][ni] = __builtin_amdgcn_mfma_f32_16x16x32_bf16(w1k1, xf[ni][1], acc[2*(q)+1][ni], 0, 0, 0);\
    }                                                                                                        \
    __builtin_amdgcn_s_setprio(0);                                                                           \
    __builtin_amdgcn_s_barrier();                                                                            \
  }

#pragma unroll 1
  for (int it = 0; it < 47; ++it) {
    const int t0 = 2 * it;
    PHASE(0, 0, stageW(1, 0, t0 + 1), );
    PHASE(0, 1, stageW(1, 1, t0 + 1), );
    PHASE(0, 2, stageX(0, 0, t0 + 2), );
    PHASE(0, 3, stageX(0, 1, t0 + 2), asm volatile("s_waitcnt vmcnt(4)" ::: "memory"));
    PHASE(1, 0, stageW(0, 0, t0 + 2), );
    PHASE(1, 1, stageW(0, 1, t0 + 2), );
    PHASE(1, 2, stageX(1, 0, t0 + 3), );
    PHASE(1, 3, stageX(1, 1, t0 + 3), asm volatile("s_waitcnt vmcnt(4)" ::: "memory"));
  }
  // peeled last iteration: steps 94 (slot0), 95 (slot1); only step95's W still needs staging
  PHASE(0, 0, stageW(1, 0, 95), );
  PHASE(0, 1, stageW(1, 1, 95), );
  PHASE(0, 2, , );
  PHASE(0, 3, , asm volatile("s_waitcnt vmcnt(0)" ::: "memory"));
  PHASE(1, 0, , );
  PHASE(1, 1, , );
  PHASE(1, 2, , );
  PHASE(1, 3, , );
#undef PHASE

  // epilogue: D row = o, col = l
  const int r4 = (lane >> 4) * 4;
  const int lbase = l0 + wn * 64 + (lane & 15);
  if (o0 < 512) {
#pragma unroll
    for (int mi = 0; mi < 8; ++mi)
#pragma unroll
      for (int ni = 0; ni < 4; ++ni) {
        int l = lbase + ni * 16;
#pragma unroll
        for (int j = 0; j < 4; ++j) {
          int o = o0 + wm * 128 + mi * 16 + r4 + j;
          vT[((size_t)b * 512 + o) * 4096 + l] = acc[mi][ni][j] + cb[o];
        }
      }
  } else {
#pragma unroll
    for (int mi = 0; mi < 8; ++mi)
#pragma unroll
      for (int ni = 0; ni < 4; ++ni) {
        int l = lbase + ni * 16;
#pragma unroll
        for (int j = 0; j < 4; ++j) {
          int o = o0 + wm * 128 + mi * 16 + r4 + j;
          int oc = o - 512;
          projsT[((size_t)((oc >> 9) * 4 + b) * 512 + (oc & 511)) * 4096 + l] = f2bf(acc[mi][ni][j] + cb[o]);
        }
      }
  }
}

// ---------------- filter GEMM: hT[ch][l] = (t @ fW + fb)*window ----------------

__launch_bounds__(256, 1)
__global__ void h_kernel(const float* __restrict__ tT, const float* __restrict__ fW,
                         const float* __restrict__ fb, const float* __restrict__ window,
                         float* __restrict__ hT) {
  __shared__ float tTs[128][64];    // 32 KiB  [d][l]
  __shared__ float fWs[128][128];   // 64 KiB  [d][ch]
  const int l0 = blockIdx.x * 64;
  const int c0 = blockIdx.y * 128;
  const int tid = threadIdx.x;
  {
    int lq = (tid & 15) * 4;     // l offset in tile
    int dr = tid >> 4;           // 0..15
#pragma unroll
    for (int d = dr; d < 128; d += 16)
      *(f32x4*)(&tTs[d][lq]) = *(const f32x4*)(tT + (size_t)d * 4096 + l0 + lq);
  }
  {
    int cq = (tid & 31) * 4;     // ch offset in tile
    int dr = tid >> 5;           // 0..7
#pragma unroll
    for (int d = dr; d < 128; d += 8)
      *(f32x4*)(&fWs[d][cq]) = *(const f32x4*)(fW + (size_t)d * 1536 + c0 + cq);
  }
  __syncthreads();
  const int lgrp = tid & 15;     // 4 l's each
  const int cg = tid >> 4;       // 0..15, 8 ch each strided 16 (conflict-free)
  float acc[8][4] = {};
#pragma unroll 4
  for (int d = 0; d < 128; ++d) {
    f32x4 tv = *(const f32x4*)(&tTs[d][lgrp * 4]);
#pragma unroll
    for (int j = 0; j < 8; ++j) {
      float wv = fWs[d][cg + 16 * j];
      acc[j][0] = fmaf(tv[0], wv, acc[j][0]);
      acc[j][1] = fmaf(tv[1], wv, acc[j][1]);
      acc[j][2] = fmaf(tv[2], wv, acc[j][2]);
      acc[j][3] = fmaf(tv[3], wv, acc[j][3]);
    }
  }
  f32x4 wl = *(const f32x4*)(window + l0 + lgrp * 4);
#pragma unroll
  for (int j = 0; j < 8; ++j) {
    int ch = c0 + cg + 16 * j;
    float fbv = fb[ch];
    f32x4 r;
    r[0] = (acc[j][0] + fbv) * wl[0];
    r[1] = (acc[j][1] + fbv) * wl[1];
    r[2] = (acc[j][2] + fbv) * wl[2];
    r[3] = (acc[j][3] + fbv) * wl[3];
    *(f32x4*)(hT + (size_t)ch * 4096 + l0 + lgrp * 4) = r;
  }
}

// ---------------- packed real FFT machinery (M=2048 complex, radix-2 Stockham) ----------------
// Per-stage compact twiddle tables: T[off_s + j] = exp(-i*pi*j/(1024>>s)), off_s = 2048-(2048>>s).
// Conflict-free: per-lane stride-1 at s=0, broadcast at high s.

__device__ __forceinline__ void fill_twiddles(float2* T, int tid) {
#pragma unroll 1
  for (int s = 0; s < 11; ++s) {
    const int sz = 1024 >> s;
    const int off = 2048 - (2048 >> s);
    for (int j = tid; j < sz; j += 256) {
      float sn, cs;
      sincosf(-PI_F * (float)j / (float)sz, &sn, &cs);
      T[off + j] = make_float2(cs, sn);
    }
  }
}

template<bool INV>
__device__ __forceinline__ void fft11(float2* X, float2* Y, const float2* T, int tid) {
  float2* src = X; float2* dst = Y;
#pragma unroll 1
  for (int s = 0; s < 11; ++s) {
    const int m = 1 << s;
    const int off = 2048 - (2048 >> s);
#pragma unroll
    for (int q = 0; q < 4; ++q) {
      const int p = tid + (q << 8);
      const int j = p >> s;
      const int jm = p & ~(m - 1);
      float2 a = src[p];
      float2 cc = src[p + 1024];
      float2 t = T[off + j];
      const float wr = t.x;
      const float wi = INV ? -t.y : t.y;
      float dx = a.x - cc.x, dy = a.y - cc.y;
      dst[p + jm]     = make_float2(a.x + cc.x, a.y + cc.y);
      dst[p + jm + m] = make_float2(dx * wr - dy * wi, dx * wi + dy * wr);
    }
    __syncthreads();
    float2* tt = src; src = dst; dst = tt;
  }
}

// untangle packed-FFT Z (of z[m]=v[2m]+i v[2m+1]) into rfft V[0..2048]
__device__ __forceinline__ void untangle(const float2* __restrict__ Z, float2* __restrict__ V, int tid) {
  for (int k = tid; k < 1024; k += 256) {
    if (k == 0) {
      float2 z0 = Z[0];
      V[0]    = make_float2(z0.x + z0.y, 0.f);
      V[2048] = make_float2(z0.x - z0.y, 0.f);
      float2 zq = Z[1024];
      V[1024] = make_float2(zq.x, -zq.y);
    } else {
      float2 zk = Z[k], zm = Z[2048 - k];
      float2 E = make_float2(0.5f * (zk.x + zm.x), 0.5f * (zk.y - zm.y));
      float2 D = make_float2(0.5f * (zk.x - zm.x), 0.5f * (zk.y + zm.y));
      float2 O = make_float2(D.y, -D.x);              // -i*D
      float sn, cs;
      __sincosf(-PI_F * (float)k * (1.0f / 2048.0f), &sn, &cs);
      float2 twO = make_float2(O.x * cs - O.y * sn, O.x * sn + O.y * cs);
      V[k]        = make_float2(E.x + twO.x, E.y + twO.y);
      V[2048 - k] = make_float2(E.x - twO.x, -(E.y - twO.y));
    }
  }
}

// filters: rfft of hT rows -> Hf[ch][0..2048]
__launch_bounds__(256, 3)
__global__ void fft_filter_r(const float* __restrict__ hT, float2* __restrict__ Hf) {
  __shared__ float2 A[2048];
  __shared__ float2 B[2048];
  __shared__ float2 T[2048];
  const int ch = blockIdx.x;
  const int tid = threadIdx.x;
  fill_twiddles(T, tid);
  const float* sig = hT + (size_t)ch * 4096;
  for (int m = tid; m < 2048; m += 256)
    A[m] = *(const float2*)(sig + 2 * m);
  __syncthreads();
  fft11<false>(A, B, T, tid);     // result in B
  float2* o = Hf + (size_t)ch * HSTR;
  for (int k = tid; k < 1024; k += 256) {
    if (k == 0) {
      float2 z0 = B[0];
      o[0]    = make_float2(z0.x + z0.y, 0.f);
      o[2048] = make_float2(z0.x - z0.y, 0.f);
      float2 zq = B[1024];
      o[1024] = make_float2(zq.x, -zq.y);
    } else {
      float2 zk = B[k], zm = B[2048 - k];
      float2 E = make_float2(0.5f * (zk.x + zm.x), 0.5f * (zk.y - zm.y));
      float2 D = make_float2(0.5f * (zk.x - zm.x), 0.5f * (zk.y + zm.y));
      float2 O = make_float2(D.y, -D.x);
      float sn, cs;
      __sincosf(-PI_F * (float)k * (1.0f / 2048.0f), &sn, &cs);
      float2 twO = make_float2(O.x * cs - O.y * sn, O.x * sn + O.y * cs);
      o[k]        = make_float2(E.x + twO.x, E.y + twO.y);
      o[2048 - k] = make_float2(E.x - twO.x, -(E.y - twO.y));
    }
  }
}

// all 3 Hyena orders fused; v stays in LDS. Per (b,c): rfft(v); x3 { *H_k; irfft; *xn_k }
__launch_bounds__(256, 3)
__global__ void fft_conv3(float* __restrict__ vT, const ushortT* __restrict__ projsT,
                          const float2* __restrict__ Hf) {
  __shared__ float2 A[2080];   // holds packed signal / spectrum V[0..2048]
  __shared__ float2 B[2048];
  __shared__ float2 T[2048];
  const int bc = blockIdx.x;   // b*512 + c
  const int c = bc & 511, b = bc >> 9;
  const int tid = threadIdx.x;
  fill_twiddles(T, tid);
  float* sig = vT + (size_t)bc * 4096;
  for (int m = tid; m < 2048; m += 256)
    A[m] = *(const float2*)(sig + 2 * m);
  __syncthreads();
  fft11<false>(A, B, T, tid);   // -> B
  untangle(B, A, tid);          // -> A = V[0..2048]
  __syncthreads();

  const float scale = 1.0f / 2048.0f;
#pragma unroll 1
  for (int k = 0; k < 3; ++k) {
    const float2* H = Hf + ((size_t)k * 512 + c) * HSTR;
    // tangle: W[j] (packed inverse input) from Y[j] = V[j]*H[j]
    for (int kk = tid; kk < 1024; kk += 256) {
      if (kk == 0) {
        float y0 = A[0].x * H[0].x;
        float yq = A[2048].x * H[2048].x;
        B[0] = make_float2(0.5f * (y0 + yq), 0.5f * (y0 - yq));
        float2 vq = A[1024], hq = H[1024];
        float2 Yq = make_float2(vq.x * hq.x - vq.y * hq.y, vq.x * hq.y + vq.y * hq.x);
        B[1024] = make_float2(Yq.x, -Yq.y);
      } else {
        float2 vk = A[kk], hk = H[kk];
        float2 vm = A[2048 - kk], hm = H[2048 - kk];
        float2 Yk = make_float2(vk.x * hk.x - vk.y * hk.y, vk.x * hk.y + vk.y * hk.x);
        float2 Ym = make_float2(vm.x * hm.x - vm.y * hm.y, vm.x * hm.y + vm.y * hm.x);
        float2 E = make_float2(0.5f * (Yk.x + Ym.x), 0.5f * (Yk.y - Ym.y));
        float2 D = make_float2(0.5f * (Yk.x - Ym.x), 0.5f * (Yk.y + Ym.y));
        float sn, cs;
        __sincosf(PI_F * (float)kk * (1.0f / 2048.0f), &sn, &cs);
        float2 twD = make_float2(D.x * cs - D.y * sn, D.x * sn + D.y * cs);
        B[kk]        = make_float2(E.x - twD.y, E.y + twD.x);
        B[2048 - kk] = make_float2(E.x + twD.y, -E.y + twD.x);
      }
    }
    __syncthreads();
    fft11<true>(B, A, T, tid);   // -> A = packed y (unscaled)
    const ushortT* xn = projsT + ((size_t)(k * 4 + b) * 512 + c) * 4096;
    if (k < 2) {
      for (int m = tid; m < 2048; m += 256) {
        unsigned int pr = *(const unsigned int*)(xn + 2 * m);
        float2 a = A[m];
        A[m] = make_float2(a.x * scale * bf2f((ushortT)(pr & 0xffffu)),
                           a.y * scale * bf2f((ushortT)(pr >> 16)));
      }
      __syncthreads();
      fft11<false>(A, B, T, tid);
      untangle(B, A, tid);
      __syncthreads();
    } else {
      for (int m = tid; m < 2048; m += 256) {
        unsigned int pr = *(const unsigned int*)(xn + 2 * m);
        float2 a = A[m];
        float2 r = make_float2(a.x * scale * bf2f((ushortT)(pr & 0xffffu)),
                               a.y * scale * bf2f((ushortT)(pr >> 16)));
        *(float2*)(sig + 2 * m) = r;
      }
    }
  }
}

// ---------------- output GEMM ----------------

__launch_bounds__(256)
__global__ void out_gemm(const float* __restrict__ vT, const float* __restrict__ oW,
                         const float* __restrict__ ob, float* __restrict__ out) {
  int l0 = blockIdx.x * 32;         // 512 blocks
  int b = l0 >> 12;
  int li = threadIdx.x & 31;
  int og = (threadIdx.x >> 5) * 4;  // 8 groups x 4 outs
  float acc[4] = {};
  const float* vb = vT + (size_t)b * 512 * 4096 + (l0 & 4095) + li;
#pragma unroll 8
  for (int c = 0; c < 512; ++c) {
    float v = vb[(size_t)c * 4096];
#pragma unroll
    for (int j = 0; j < 4; ++j)
      acc[j] = fmaf(v, oW[c * 32 + og + j], acc[j]);
  }
  float* op = out + (size_t)(l0 + li) * 32 + og;
  f32x4 r;
  r[0] = acc[0] + ob[og];     r[1] = acc[1] + ob[og + 1];
  r[2] = acc[2] + ob[og + 2]; r[3] = acc[3] + ob[og + 3];
  *(f32x4*)op = r;
}

// ---------------- diagnostics ----------------

__global__ void ws_sentinel(float* __restrict__ out) {
  if (threadIdx.x == 0) out[0] = -31337.0f;
}

// ---------------- launch ----------------

extern "C" void kernel_launch(void* const* d_in, const int* in_sizes, int n_in,
                              void* d_out, int out_size, void* d_ws, size_t ws_size,
                              hipStream_t stream) {
  (void)in_sizes; (void)n_in; (void)out_size;
  const float* u  = (const float*)d_in[0];
  const float* pW = (const float*)d_in[1];
  const float* pb = (const float*)d_in[2];
  const float* cW = (const float*)d_in[3];
  const float* cb = (const float*)d_in[4];
  const float* fW = (const float*)d_in[5];
  const float* fb = (const float*)d_in[6];
  const float* oW = (const float*)d_in[7];
  const float* ob = (const float*)d_in[8];
  float* out = (float*)d_out;

  char* ws = (char*)d_ws;
  // persistent region
  ushortT* Apad   = (ushortT*)(ws);                    // 67,141,632  (4x4098x2048 bf16)
  ushortT* Wt     = (ushortT*)(ws + 67141632);         // 25,165,824  (3x2048x2048 bf16)
  float2*  Hf     = (float2*) (ws + 92307456);         // 25,264,128  (1536 x HSTR c64, half-spectrum)
  float*   vT     = (float*)  (ws + 117571584);        // 33,554,432  (4x512x4096 f32)
  ushortT* projsT = (ushortT*)(ws + 151126016);        // 50,331,648  (12x512x4096 bf16)
  const size_t total = 201457664;                      // 192.1 MiB
  // scratch overlay on [vT, end) — all dead before gemm_conv8 writes vT/projsT
  char* S = (char*)vT;
  ushortT* u_bf   = (ushortT*)(S);                     // 16,777,216
  ushortT* pWt    = (ushortT*)(S + 16777216);          //  2,097,152
  float*   tT     = (float*)  (S + 18874368);          //  2,097,152
  float*   window = (float*)  (S + 20971520);          //     16,384
  float*   hT     = (float*)  (S + 20987904);          // 25,165,824 -> ends 46,153,728 (< 83,886,080)

  if (total > ws_size) {           // diagnostic: distinguishable failure signature
    ws_sentinel<<<1, 64, 0, stream>>>(out);
    return;
  }

  convert_u<<<8192, 256, 0, stream>>>(u, u_bf);
  convert_pW<<<dim3(64, 16), dim3(32, 8), 0, stream>>>(pW, pWt);
  convert_cW<<<16384, 256, 0, stream>>>(cW, Wt);
  zero_pad<<<64, 256, 0, stream>>>(Apad);
  pe_window<<<1024, 256, 0, stream>>>(tT, window);
  gemm_A<<<dim3(128, 16), 256, 0, stream>>>(u_bf, pWt, pb, Apad);       // u_bf,pWt dead after
  h_kernel<<<dim3(64, 12), 256, 0, stream>>>(tT, fW, fb, window, hT);   // tT,window dead after
  fft_filter_r<<<1536, 256, 0, stream>>>(hT, Hf);                       // hT dead after
  gemm_conv8<<<512, 512, 0, stream>>>(Apad, Wt, cb, vT, projsT);
  fft_conv3<<<2048, 256, 0, stream>>>(vT, projsT, Hf);
  out_gemm<<<512, 256, 0, stream>>>(vT, oW, ob, out);
}

// Round 6
// 454.706 us; speedup vs baseline: 8.4407x; 1.4826x over previous
//
#include <hip/hip_runtime.h>

typedef __attribute__((ext_vector_type(8))) short short8;
typedef __attribute__((ext_vector_type(4))) float f32x4;
typedef __attribute__((ext_vector_type(4))) unsigned short ushort4v;
typedef unsigned short ushortT;

#define PADROWS 4098
#define HSTR 2056   // half-spectrum row stride (float2), 64B-aligned
#define PI_F 3.14159265358979323f

__device__ __forceinline__ ushortT f2bf(float f) {
  union { float f; unsigned int u; } v; v.f = f;
  unsigned int r = (v.u + 0x7FFFu + ((v.u >> 16) & 1u)) >> 16;
  return (ushortT)r;
}
__device__ __forceinline__ float bf2f(ushortT b) {
  union { unsigned int u; float f; } v; v.u = ((unsigned int)b) << 16;
  return v.f;
}

__device__ __forceinline__ void gl2lds16(const void* g, void* l) {
  __builtin_amdgcn_global_load_lds((const __attribute__((address_space(1))) void*)g,
                                   (__attribute__((address_space(3))) void*)l, 16, 0, 0);
}

// ---------------- conversions ----------------

// flat f32 -> bf16 cast (4 elems/thread)
__global__ void cast_flat(const float* __restrict__ in, ushortT* __restrict__ outb) {
  size_t idx = (size_t)blockIdx.x * 256 + threadIdx.x;
  f32x4 v = *(const f32x4*)(in + idx * 4);
  ushort4v r;
  r[0] = f2bf(v[0]); r[1] = f2bf(v[1]); r[2] = f2bf(v[2]); r[3] = f2bf(v[3]);
  *(ushort4v*)(outb + idx * 4) = r;
}

// u (4,4096,512) f32 -> Upad (4,4098,512) bf16 rows shifted +1
__global__ void convert_u_pad(const float* __restrict__ in, ushortT* __restrict__ up) {
  size_t idx = (size_t)blockIdx.x * 256 + threadIdx.x;  // 2,097,152 quads
  f32x4 v = *(const f32x4*)(in + idx * 4);
  ushort4v r;
  r[0] = f2bf(v[0]); r[1] = f2bf(v[1]); r[2] = f2bf(v[2]); r[3] = f2bf(v[3]);
  size_t g = idx * 4;
  int col = (int)(g & 511);
  int l = (int)(g >> 9);
  int b = l >> 12;
  *(ushort4v*)(up + ((size_t)b * PADROWS + (l & 4095) + 1) * 512 + col) = r;
}

__global__ void zero_pad_u(ushortT* __restrict__ Upad) {
  int idx = blockIdx.x * 256 + threadIdx.x;   // 4096 = 4b * 2r * 512c
  int col = idx & 511;
  int r = (idx >> 9) & 1;
  int b = idx >> 10;
  Upad[((size_t)b * PADROWS + (r ? 4097 : 0)) * 512 + col] = 0;
}

// cW (2048,2048,3) f32 -> Wt[h][o][i] bf16
__global__ void convert_cW(const float* __restrict__ cW, ushortT* __restrict__ Wt) {
  size_t idx = (size_t)blockIdx.x * 256 + threadIdx.x;  // (o,i)
  const float* p = cW + idx * 3;
  float w0 = p[0], w1 = p[1], w2 = p[2];
  Wt[idx]           = f2bf(w0);
  Wt[idx + 4194304] = f2bf(w1);
  Wt[idx + 8388608] = f2bf(w2);
}

// pbC[o][h] = sum_i pb[i]*cW[o,i,h]; biasC[o] = cb[o] + sum_h pbC
__global__ void pbc_kernel(const float* __restrict__ cW, const float* __restrict__ pb,
                           const float* __restrict__ cb, float* __restrict__ biasC,
                           float* __restrict__ pbC0, float* __restrict__ pbC2) {
  int o = blockIdx.x;
  int tid = threadIdx.x;
  float s0 = 0.f, s1 = 0.f, s2 = 0.f;
  const float* base = cW + (size_t)o * 2048 * 3;
  for (int i = tid; i < 2048; i += 256) {
    float p = pb[i];
    s0 = fmaf(p, base[i * 3 + 0], s0);
    s1 = fmaf(p, base[i * 3 + 1], s1);
    s2 = fmaf(p, base[i * 3 + 2], s2);
  }
#pragma unroll
  for (int off = 32; off >= 1; off >>= 1) {
    s0 += __shfl_down(s0, off);
    s1 += __shfl_down(s1, off);
    s2 += __shfl_down(s2, off);
  }
  __shared__ float red[4][3];
  if ((tid & 63) == 0) { red[tid >> 6][0] = s0; red[tid >> 6][1] = s1; red[tid >> 6][2] = s2; }
  __syncthreads();
  if (tid == 0) {
    float a0 = red[0][0] + red[1][0] + red[2][0] + red[3][0];
    float a1 = red[0][1] + red[1][1] + red[2][1] + red[3][1];
    float a2 = red[0][2] + red[1][2] + red[2][2] + red[3][2];
    biasC[o] = cb[o] + a0 + a1 + a2;
    pbC0[o] = a0;
    pbC2[o] = a2;
  }
}

// tT[128][4096], window[4096]
__global__ void pe_window(float* __restrict__ tT, float* __restrict__ window) {
  int idx = blockIdx.x * 256 + threadIdx.x;  // 262144
  int l = idx & 4095, d2 = idx >> 12;        // d2 in 0..63
  float dv = expf(-9.210340371976184f * (float)(2 * d2) / 128.0f);
  float ang = (float)l * dv;
  tT[(size_t)(2 * d2) * 4096 + l] = sinf(ang);
  tT[(size_t)(2 * d2 + 1) * 4096 + l] = cosf(ang);
  if (d2 == 0)
    window[l] = 0.5f * (1.0f - cosf(6.283185307179586f * (float)l / 4095.0f));
}

// ---------------- fold GEMM: cWf[h][o][j] = sum_i Wt[h][o][i] * pW[j][i]  (128x128 tile) ----------------

__launch_bounds__(256, 2)
__global__ void gemm_fold(const ushortT* __restrict__ Wt, const ushortT* __restrict__ pW_bf,
                          ushortT* __restrict__ cWf) {
  __shared__ alignas(16) ushortT As[128 * 64];
  __shared__ alignas(16) ushortT Bs[128 * 64];
  const int tid = threadIdx.x;
  const int lane = tid & 63, w = tid >> 6;
  const int wm = w >> 1, wn = w & 1;
  const int tm = blockIdx.x, tn = blockIdx.y, h = blockIdx.z;
  const ushortT* A = Wt + (size_t)h * 4194304;
  f32x4 acc[4][4] = {};
#pragma unroll 1
  for (int kt = 0; kt < 32; ++kt) {
    const int i0 = kt * 64;
#pragma unroll
    for (int i = 0; i < 4; ++i) {
      int ldsoff = (i * 4 + w) * 1024;
      int m = ((i * 4 + w) << 3) + (lane >> 3);
      int col = (lane & 7) * 8;
      gl2lds16(A + (size_t)(tm * 128 + m) * 2048 + i0 + col, (char*)As + ldsoff);
      gl2lds16(pW_bf + (size_t)(tn * 128 + m) * 2048 + i0 + col, (char*)Bs + ldsoff);
    }
    __syncthreads();
#pragma unroll
    for (int ks = 0; ks < 2; ++ks) {
      short8 av[4], bv[4];
#pragma unroll
      for (int mi = 0; mi < 4; ++mi) {
        int row = wm * 64 + mi * 16 + (lane & 15);
        av[mi] = *(const short8*)(As + row * 64 + (ks * 4 + (lane >> 4)) * 8);
      }
#pragma unroll
      for (int ni = 0; ni < 4; ++ni) {
        int row = wn * 64 + ni * 16 + (lane & 15);
        bv[ni] = *(const short8*)(Bs + row * 64 + (ks * 4 + (lane >> 4)) * 8);
      }
#pragma unroll
      for (int mi = 0; mi < 4; ++mi)
#pragma unroll
        for (int ni = 0; ni < 4; ++ni)
          acc[mi][ni] = __builtin_amdgcn_mfma_f32_16x16x32_bf16(av[mi], bv[ni], acc[mi][ni], 0, 0, 0);
    }
    __syncthreads();
  }
#pragma unroll
  for (int mi = 0; mi < 4; ++mi)
#pragma unroll
    for (int ni = 0; ni < 4; ++ni) {
      int jc = tn * 128 + wn * 64 + ni * 16 + (lane & 15);
#pragma unroll
      for (int j = 0; j < 4; ++j) {
        int o = tm * 128 + wm * 64 + mi * 16 + (lane >> 4) * 4 + j;
        cWf[((size_t)h * 2048 + o) * 512 + jc] = f2bf(acc[mi][ni][j]);
      }
    }
}

// ---------------- conv GEMM: 256x256 8-phase pipeline over folded weights, K=1536 ----------------
// z[b,l,o] = sum_h sum_j Upad[b,l+h,j]*cWf[h][o][j] + biasC[o] (- pbC0[o] at l=0, - pbC2[o] at l=4095)
// K-steps t=0..23, h-minor: t = 3q+h, j0 = 64q (adjacent t re-read same Upad rows -> L2-hot).

__launch_bounds__(512, 2)
__global__ void gemm_conv8(const ushortT* __restrict__ Upad, const ushortT* __restrict__ cWf,
                           const float* __restrict__ biasC, const float* __restrict__ pbC0,
                           const float* __restrict__ pbC2, float* __restrict__ vT,
                           ushortT* __restrict__ projsT) {
  __shared__ ushortT lds[2][2][16384];  // [slot][0=W,1=X][256 rows x 64 bf16]
  const int tid = threadIdx.x;
  const int lane = tid & 63, w = tid >> 6;   // 8 waves
  const int wm = w >> 2, wn = w & 3;         // 2 x 4
  int raw = blockIdx.x;                       // 512 wgs
  int wg  = (raw & 7) * 64 + (raw >> 3);      // bijective XCD chunking (512 % 8 == 0)
  const int o0 = (wg >> 6) << 8;              // o tile 0..7
  const int nt = wg & 63;
  const int b  = nt >> 4;
  const int l0 = (nt & 15) << 8;

  f32x4 acc[8][4] = {};
  short8 xf[4][2];

  const int sm = tid >> 3;                      // staging row 0..63 (and +64)
  const int sw1 = ((tid & 7) ^ (sm & 7)) << 3;  // pre-swizzled source chunk (elements)

  auto stageW = [&](int slot, int half, int t) {
    int q = (t * 21846) >> 16, h = t - 3 * q, j0 = q << 6;
    size_t grow = (size_t)(h * 2048 + o0 + half * 128 + sm);
    char* dst = (char*)&lds[slot][0][0] + half * 16384 + w * 1024;
    gl2lds16(cWf + grow * 512 + j0 + sw1, dst);
    gl2lds16(cWf + (grow + 64) * 512 + j0 + sw1, dst + 8192);
  };
  auto stageX = [&](int slot, int half, int t) {
    int q = (t * 21846) >> 16, h = t - 3 * q, j0 = q << 6;
    size_t grow = (size_t)b * PADROWS + l0 + h + half * 128 + sm;
    char* dst = (char*)&lds[slot][1][0] + half * 16384 + w * 1024;
    gl2lds16(Upad + grow * 512 + j0 + sw1, dst);
    gl2lds16(Upad + (grow + 64) * 512 + j0 + sw1, dst + 8192);
  };
  auto ldsW = [&](int slot, int mi, int ks) -> short8 {
    int row = wm * 128 + mi * 16 + (lane & 15);
    int ch = (ks * 4 + (lane >> 4)) ^ (row & 7);
    return *(const short8*)&lds[slot][0][row * 64 + ch * 8];
  };
  auto ldsX = [&](int slot, int ni, int ks) -> short8 {
    int row = wn * 64 + ni * 16 + (lane & 15);
    int ch = (ks * 4 + (lane >> 4)) ^ (row & 7);
    return *(const short8*)&lds[slot][1][row * 64 + ch * 8];
  };

  // prologue: step0 W+X -> slot0; step1 X -> slot1 (step1 W staged in-loop ph0/ph1)
  stageW(0, 0, 0); stageW(0, 1, 0);
  stageX(0, 0, 0); stageX(0, 1, 0);
  stageX(1, 0, 1); stageX(1, 1, 1);
  asm volatile("s_waitcnt vmcnt(0)" ::: "memory");
  __builtin_amdgcn_s_barrier();

#define PHASE(slot, q, STAGECODE, VMCODE)                                                                    \
  {                                                                                                          \
    short8 w0k0 = ldsW(slot, 2*(q), 0), w0k1 = ldsW(slot, 2*(q), 1);                                         \
    short8 w1k0 = ldsW(slot, 2*(q)+1, 0), w1k1 = ldsW(slot, 2*(q)+1, 1);                                     \
    if ((q) == 0) {                                                                                          \
      _Pragma("unroll")                                                                                      \
      for (int ni = 0; ni < 4; ++ni) {                                                                       \
        xf[ni][0] = ldsX(slot, ni, 0);                                                                       \
        xf[ni][1] = ldsX(slot, ni, 1);                                                                       \
      }                                                                                                      \
    }                                                                                                        \
    STAGECODE;                                                                                               \
    VMCODE;                                                                                                  \
    __builtin_amdgcn_s_barrier();                                                                            \
    asm volatile("s_waitcnt lgkmcnt(0)" ::: "memory");                                                       \
    __builtin_amdgcn_sched_barrier(0);                                                                       \
    __builtin_amdgcn_s_setprio(1);                                                                           \
    _Pragma("unroll")                                                                                        \
    for (int ni = 0; ni < 4; ++ni) {                                                                         \
      acc[2*(q)][ni]   = __builtin_amdgcn_mfma_f32_16x16x32_bf16(w0k0, xf[ni][0], acc[2*(q)][ni], 0, 0, 0);  \
      acc[2*(q)][ni]   = __builtin_amdgcn_mfma_f32_16x16x32_bf16(w0k1, xf[ni][1], acc[2*(q)][ni], 0, 0, 0);  \
      acc[2*(q)+1][ni] = __builtin_amdgcn_mfma_f32_16x16x32_bf16(w1k0, xf[ni][0], acc[2*(q)+1][ni], 0, 0, 0);\
      acc[2*(q)+1][ni] = __builtin_amdgcn_mfma_f32_16x16x32_bf16(w1k1, xf[ni][1], acc[2*(q)+1][ni], 0, 0, 0);\
    }                                                                                                        \
    __builtin_amdgcn_s_setprio(0);                                                                           \
    __builtin_amdgcn_s_barrier();                                                                            \
  }

#pragma unroll 1
  for (int it = 0; it < 11; ++it) {
    const int t0 = 2 * it;
    PHASE(0, 0, stageW(1, 0, t0 + 1), );
    PHASE(0, 1, stageW(1, 1, t0 + 1), );
    PHASE(0, 2, stageX(0, 0, t0 + 2), );
    PHASE(0, 3, stageX(0, 1, t0 + 2), asm volatile("s_waitcnt vmcnt(4)" ::: "memory"));
    PHASE(1, 0, stageW(0, 0, t0 + 2), );
    PHASE(1, 1, stageW(0, 1, t0 + 2), );
    PHASE(1, 2, stageX(1, 0, t0 + 3), );
    PHASE(1, 3, stageX(1, 1, t0 + 3), asm volatile("s_waitcnt vmcnt(4)" ::: "memory"));
  }
  // peeled last iteration: steps 22 (slot0), 23 (slot1); only step23's W still needs staging
  PHASE(0, 0, stageW(1, 0, 23), );
  PHASE(0, 1, stageW(1, 1, 23), );
  PHASE(0, 2, , );
  PHASE(0, 3, , asm volatile("s_waitcnt vmcnt(0)" ::: "memory"));
  PHASE(1, 0, , );
  PHASE(1, 1, , );
  PHASE(1, 2, , );
  PHASE(1, 3, , );
#undef PHASE

  // epilogue: D row = o, col = l
  const int r4 = (lane >> 4) * 4;
  const int lbase = l0 + wn * 64 + (lane & 15);
  if (o0 < 512) {
#pragma unroll
    for (int mi = 0; mi < 8; ++mi)
#pragma unroll
      for (int ni = 0; ni < 4; ++ni) {
        int l = lbase + ni * 16;
#pragma unroll
        for (int j = 0; j < 4; ++j) {
          int o = o0 + wm * 128 + mi * 16 + r4 + j;
          float val = acc[mi][ni][j] + biasC[o];
          if (l == 0) val -= pbC0[o];
          if (l == 4095) val -= pbC2[o];
          vT[((size_t)b * 512 + o) * 4096 + l] = val;
        }
      }
  } else {
#pragma unroll
    for (int mi = 0; mi < 8; ++mi)
#pragma unroll
      for (int ni = 0; ni < 4; ++ni) {
        int l = lbase + ni * 16;
#pragma unroll
        for (int j = 0; j < 4; ++j) {
          int o = o0 + wm * 128 + mi * 16 + r4 + j;
          float val = acc[mi][ni][j] + biasC[o];
          if (l == 0) val -= pbC0[o];
          if (l == 4095) val -= pbC2[o];
          int oc = o - 512;
          projsT[((size_t)((oc >> 9) * 4 + b) * 512 + (oc & 511)) * 4096 + l] = f2bf(val);
        }
      }
  }
}

// ---------------- filter GEMM: hT[ch][l] = (t @ fW + fb)*window ----------------

__launch_bounds__(256, 1)
__global__ void h_kernel(const float* __restrict__ tT, const float* __restrict__ fW,
                         const float* __restrict__ fb, const float* __restrict__ window,
                         float* __restrict__ hT) {
  __shared__ float tTs[128][64];    // 32 KiB  [d][l]
  __shared__ float fWs[128][128];   // 64 KiB  [d][ch]
  const int l0 = blockIdx.x * 64;
  const int c0 = blockIdx.y * 128;
  const int tid = threadIdx.x;
  {
    int lq = (tid & 15) * 4;
    int dr = tid >> 4;
#pragma unroll
    for (int d = dr; d < 128; d += 16)
      *(f32x4*)(&tTs[d][lq]) = *(const f32x4*)(tT + (size_t)d * 4096 + l0 + lq);
  }
  {
    int cq = (tid & 31) * 4;
    int dr = tid >> 5;
#pragma unroll
    for (int d = dr; d < 128; d += 8)
      *(f32x4*)(&fWs[d][cq]) = *(const f32x4*)(fW + (size_t)d * 1536 + c0 + cq);
  }
  __syncthreads();
  const int lgrp = tid & 15;
  const int cg = tid >> 4;
  float acc[8][4] = {};
#pragma unroll 4
  for (int d = 0; d < 128; ++d) {
    f32x4 tv = *(const f32x4*)(&tTs[d][lgrp * 4]);
#pragma unroll
    for (int j = 0; j < 8; ++j) {
      float wv = fWs[d][cg + 16 * j];
      acc[j][0] = fmaf(tv[0], wv, acc[j][0]);
      acc[j][1] = fmaf(tv[1], wv, acc[j][1]);
      acc[j][2] = fmaf(tv[2], wv, acc[j][2]);
      acc[j][3] = fmaf(tv[3], wv, acc[j][3]);
    }
  }
  f32x4 wl = *(const f32x4*)(window + l0 + lgrp * 4);
#pragma unroll
  for (int j = 0; j < 8; ++j) {
    int ch = c0 + cg + 16 * j;
    float fbv = fb[ch];
    f32x4 r;
    r[0] = (acc[j][0] + fbv) * wl[0];
    r[1] = (acc[j][1] + fbv) * wl[1];
    r[2] = (acc[j][2] + fbv) * wl[2];
    r[3] = (acc[j][3] + fbv) * wl[3];
    *(f32x4*)(hT + (size_t)ch * 4096 + l0 + lgrp * 4) = r;
  }
}

// ---------------- packed real FFT machinery (M=2048 complex, radix-2 Stockham) ----------------

__device__ __forceinline__ void fill_twiddles(float2* T, int tid) {
#pragma unroll 1
  for (int s = 0; s < 11; ++s) {
    const int sz = 1024 >> s;
    const int off = 2048 - (2048 >> s);
    for (int j = tid; j < sz; j += 256) {
      float sn, cs;
      sincosf(-PI_F * (float)j / (float)sz, &sn, &cs);
      T[off + j] = make_float2(cs, sn);
    }
  }
}

template<bool INV>
__device__ __forceinline__ void fft11(float2* X, float2* Y, const float2* T, int tid) {
  float2* src = X; float2* dst = Y;
#pragma unroll 1
  for (int s = 0; s < 11; ++s) {
    const int m = 1 << s;
    const int off = 2048 - (2048 >> s);
#pragma unroll
    for (int q = 0; q < 4; ++q) {
      const int p = tid + (q << 8);
      const int j = p >> s;
      const int jm = p & ~(m - 1);
      float2 a = src[p];
      float2 cc = src[p + 1024];
      float2 t = T[off + j];
      const float wr = t.x;
      const float wi = INV ? -t.y : t.y;
      float dx = a.x - cc.x, dy = a.y - cc.y;
      dst[p + jm]     = make_float2(a.x + cc.x, a.y + cc.y);
      dst[p + jm + m] = make_float2(dx * wr - dy * wi, dx * wi + dy * wr);
    }
    __syncthreads();
    float2* tt = src; src = dst; dst = tt;
  }
}

__device__ __forceinline__ void untangle(const float2* __restrict__ Z, float2* __restrict__ V, int tid) {
  for (int k = tid; k < 1024; k += 256) {
    if (k == 0) {
      float2 z0 = Z[0];
      V[0]    = make_float2(z0.x + z0.y, 0.f);
      V[2048] = make_float2(z0.x - z0.y, 0.f);
      float2 zq = Z[1024];
      V[1024] = make_float2(zq.x, -zq.y);
    } else {
      float2 zk = Z[k], zm = Z[2048 - k];
      float2 E = make_float2(0.5f * (zk.x + zm.x), 0.5f * (zk.y - zm.y));
      float2 D = make_float2(0.5f * (zk.x - zm.x), 0.5f * (zk.y + zm.y));
      float2 O = make_float2(D.y, -D.x);              // -i*D
      float sn, cs;
      __sincosf(-PI_F * (float)k * (1.0f / 2048.0f), &sn, &cs);
      float2 twO = make_float2(O.x * cs - O.y * sn, O.x * sn + O.y * cs);
      V[k]        = make_float2(E.x + twO.x, E.y + twO.y);
      V[2048 - k] = make_float2(E.x - twO.x, -(E.y - twO.y));
    }
  }
}

__launch_bounds__(256, 3)
__global__ void fft_filter_r(const float* __restrict__ hT, float2* __restrict__ Hf) {
  __shared__ float2 A[2048];
  __shared__ float2 B[2048];
  __shared__ float2 T[2048];
  const int ch = blockIdx.x;
  const int tid = threadIdx.x;
  fill_twiddles(T, tid);
  const float* sig = hT + (size_t)ch * 4096;
  for (int m = tid; m < 2048; m += 256)
    A[m] = *(const float2*)(sig + 2 * m);
  __syncthreads();
  fft11<false>(A, B, T, tid);     // result in B
  float2* o = Hf + (size_t)ch * HSTR;
  for (int k = tid; k < 1024; k += 256) {
    if (k == 0) {
      float2 z0 = B[0];
      o[0]    = make_float2(z0.x + z0.y, 0.f);
      o[2048] = make_float2(z0.x - z0.y, 0.f);
      float2 zq = B[1024];
      o[1024] = make_float2(zq.x, -zq.y);
    } else {
      float2 zk = B[k], zm = B[2048 - k];
      float2 E = make_float2(0.5f * (zk.x + zm.x), 0.5f * (zk.y - zm.y));
      float2 D = make_float2(0.5f * (zk.x - zm.x), 0.5f * (zk.y + zm.y));
      float2 O = make_float2(D.y, -D.x);
      float sn, cs;
      __sincosf(-PI_F * (float)k * (1.0f / 2048.0f), &sn, &cs);
      float2 twO = make_float2(O.x * cs - O.y * sn, O.x * sn + O.y * cs);
      o[k]        = make_float2(E.x + twO.x, E.y + twO.y);
      o[2048 - k] = make_float2(E.x - twO.x, -(E.y - twO.y));
    }
  }
}

__launch_bounds__(256, 3)
__global__ void fft_conv3(float* __restrict__ vT, const ushortT* __restrict__ projsT,
                          const float2* __restrict__ Hf) {
  __shared__ float2 A[2080];
  __shared__ float2 B[2048];
  __shared__ float2 T[2048];
  const int bc = blockIdx.x;   // b*512 + c
  const int c = bc & 511, b = bc >> 9;
  const int tid = threadIdx.x;
  fill_twiddles(T, tid);
  float* sig = vT + (size_t)bc * 4096;
  for (int m = tid; m < 2048; m += 256)
    A[m] = *(const float2*)(sig + 2 * m);
  __syncthreads();
  fft11<false>(A, B, T, tid);   // -> B
  untangle(B, A, tid);          // -> A = V[0..2048]
  __syncthreads();

  const float scale = 1.0f / 2048.0f;
#pragma unroll 1
  for (int k = 0; k < 3; ++k) {
    const float2* H = Hf + ((size_t)k * 512 + c) * HSTR;
    for (int kk = tid; kk < 1024; kk += 256) {
      if (kk == 0) {
        float y0 = A[0].x * H[0].x;
        float yq = A[2048].x * H[2048].x;
        B[0] = make_float2(0.5f * (y0 + yq), 0.5f * (y0 - yq));
        float2 vq = A[1024], hq = H[1024];
        float2 Yq = make_float2(vq.x * hq.x - vq.y * hq.y, vq.x * hq.y + vq.y * hq.x);
        B[1024] = make_float2(Yq.x, -Yq.y);
      } else {
        float2 vk = A[kk], hk = H[kk];
        float2 vm = A[2048 - kk], hm = H[2048 - kk];
        float2 Yk = make_float2(vk.x * hk.x - vk.y * hk.y, vk.x * hk.y + vk.y * hk.x);
        float2 Ym = make_float2(vm.x * hm.x - vm.y * hm.y, vm.x * hm.y + vm.y * hm.x);
        float2 E = make_float2(0.5f * (Yk.x + Ym.x), 0.5f * (Yk.y - Ym.y));
        float2 D = make_float2(0.5f * (Yk.x - Ym.x), 0.5f * (Yk.y + Ym.y));
        float sn, cs;
        __sincosf(PI_F * (float)kk * (1.0f / 2048.0f), &sn, &cs);
        float2 twD = make_float2(D.x * cs - D.y * sn, D.x * sn + D.y * cs);
        B[kk]        = make_float2(E.x - twD.y, E.y + twD.x);
        B[2048 - kk] = make_float2(E.x + twD.y, -E.y + twD.x);
      }
    }
    __syncthreads();
    fft11<true>(B, A, T, tid);   // -> A = packed y (unscaled)
    const ushortT* xn = projsT + ((size_t)(k * 4 + b) * 512 + c) * 4096;
    if (k < 2) {
      for (int m = tid; m < 2048; m += 256) {
        unsigned int pr = *(const unsigned int*)(xn + 2 * m);
        float2 a = A[m];
        A[m] = make_float2(a.x * scale * bf2f((ushortT)(pr & 0xffffu)),
                           a.y * scale * bf2f((ushortT)(pr >> 16)));
      }
      __syncthreads();
      fft11<false>(A, B, T, tid);
      untangle(B, A, tid);
      __syncthreads();
    } else {
      for (int m = tid; m < 2048; m += 256) {
        unsigned int pr = *(const unsigned int*)(xn + 2 * m);
        float2 a = A[m];
        float2 r = make_float2(a.x * scale * bf2f((ushortT)(pr & 0xffffu)),
                               a.y * scale * bf2f((ushortT)(pr >> 16)));
        *(float2*)(sig + 2 * m) = r;
      }
    }
  }
}

// ---------------- output GEMM ----------------

__launch_bounds__(256)
__global__ void out_gemm(const float* __restrict__ vT, const float* __restrict__ oW,
                         const float* __restrict__ ob, float* __restrict__ out) {
  int l0 = blockIdx.x * 32;         // 512 blocks
  int b = l0 >> 12;
  int li = threadIdx.x & 31;
  int og = (threadIdx.x >> 5) * 4;  // 8 groups x 4 outs
  float acc[4] = {};
  const float* vb = vT + (size_t)b * 512 * 4096 + (l0 & 4095) + li;
#pragma unroll 8
  for (int c = 0; c < 512; ++c) {
    float v = vb[(size_t)c * 4096];
#pragma unroll
    for (int j = 0; j < 4; ++j)
      acc[j] = fmaf(v, oW[c * 32 + og + j], acc[j]);
  }
  float* op = out + (size_t)(l0 + li) * 32 + og;
  f32x4 r;
  r[0] = acc[0] + ob[og];     r[1] = acc[1] + ob[og + 1];
  r[2] = acc[2] + ob[og + 2]; r[3] = acc[3] + ob[og + 3];
  *(f32x4*)op = r;
}

// ---------------- diagnostics ----------------

__global__ void ws_sentinel(float* __restrict__ out) {
  if (threadIdx.x == 0) out[0] = -31337.0f;
}

// ---------------- launch ----------------

extern "C" void kernel_launch(void* const* d_in, const int* in_sizes, int n_in,
                              void* d_out, int out_size, void* d_ws, size_t ws_size,
                              hipStream_t stream) {
  (void)in_sizes; (void)n_in; (void)out_size;
  const float* u  = (const float*)d_in[0];
  const float* pW = (const float*)d_in[1];
  const float* pb = (const float*)d_in[2];
  const float* cW = (const float*)d_in[3];
  const float* cb = (const float*)d_in[4];
  const float* fW = (const float*)d_in[5];
  const float* fb = (const float*)d_in[6];
  const float* oW = (const float*)d_in[7];
  const float* ob = (const float*)d_in[8];
  float* out = (float*)d_out;

  char* ws = (char*)d_ws;
  // persistent region
  ushortT* Upad   = (ushortT*)(ws);                    // 16,785,408  (4x4098x512 bf16)
  ushortT* cWf    = (ushortT*)(ws + 16785408);         //  6,291,456  (3x2048x512 bf16)
  float*   biasC  = (float*)  (ws + 23076864);         //      8,192
  float*   pbC0   = (float*)  (ws + 23085056);         //      8,192
  float*   pbC2   = (float*)  (ws + 23093248);         //      8,192
  float2*  Hf     = (float2*) (ws + 23101440);         // 25,264,128  (1536 x HSTR c64)
  float*   vT     = (float*)  (ws + 48365568);         // 33,554,432  (4x512x4096 f32)
  ushortT* projsT = (ushortT*)(ws + 81920000);         // 50,331,648  (12x512x4096 bf16)
  const size_t total = 132251648;                      // 126.1 MiB
  // scratch overlay on [vT, end) — all dead before gemm_conv8 writes vT/projsT
  char* S = (char*)vT;
  ushortT* Wt     = (ushortT*)(S);                     // 25,165,824  (3x2048x2048 bf16)
  ushortT* pW_bf  = (ushortT*)(S + 25165824);          //  2,097,152  (512x2048 bf16)
  float*   tT     = (float*)  (S + 27262976);          //  2,097,152
  float*   window = (float*)  (S + 29360128);          //     16,384
  float*   hT     = (float*)  (S + 29376512);          // 25,165,824 -> ends 54,542,336 (< 83,886,080)

  if (total > ws_size) {           // diagnostic: distinguishable failure signature
    ws_sentinel<<<1, 64, 0, stream>>>(out);
    return;
  }

  convert_u_pad<<<8192, 256, 0, stream>>>(u, Upad);
  zero_pad_u<<<16, 256, 0, stream>>>(Upad);
  cast_flat<<<1024, 256, 0, stream>>>(pW, pW_bf);
  convert_cW<<<16384, 256, 0, stream>>>(cW, Wt);
  pbc_kernel<<<2048, 256, 0, stream>>>(cW, pb, cb, biasC, pbC0, pbC2);
  gemm_fold<<<dim3(16, 4, 3), 256, 0, stream>>>(Wt, pW_bf, cWf);        // Wt,pW_bf dead after
  pe_window<<<1024, 256, 0, stream>>>(tT, window);
  h_kernel<<<dim3(64, 12), 256, 0, stream>>>(tT, fW, fb, window, hT);   // tT,window dead after
  fft_filter_r<<<1536, 256, 0, stream>>>(hT, Hf);                       // hT dead after
  gemm_conv8<<<512, 512, 0, stream>>>(Upad, cWf, biasC, pbC0, pbC2, vT, projsT);
  fft_conv3<<<2048, 256, 0, stream>>>(vT, projsT, Hf);
  out_gemm<<<512, 256, 0, stream>>>(vT, oW, ob, out);
}

// Round 7
// 352.839 us; speedup vs baseline: 10.8775x; 1.2887x over previous
//
#include <hip/hip_runtime.h>

typedef __attribute__((ext_vector_type(8))) short short8;
typedef __attribute__((ext_vector_type(4))) float f32x4;
typedef __attribute__((ext_vector_type(4))) unsigned short ushort4v;
typedef unsigned short ushortT;

#define PADROWS 4098
#define PI_F 3.14159265358979323f
// LDS bank-spread swizzle for float2 arrays (bijective: XOR low4 with bits 4..7)
#define PHYS(i) ((i) ^ (((i) >> 4) & 15))

__device__ __forceinline__ ushortT f2bf(float f) {
  union { float f; unsigned int u; } v; v.f = f;
  unsigned int r = (v.u + 0x7FFFu + ((v.u >> 16) & 1u)) >> 16;
  return (ushortT)r;
}
__device__ __forceinline__ float bf2f(ushortT b) {
  union { unsigned int u; float f; } v; v.u = ((unsigned int)b) << 16;
  return v.f;
}

__device__ __forceinline__ void gl2lds16(const void* g, void* l) {
  __builtin_amdgcn_global_load_lds((const __attribute__((address_space(1))) void*)g,
                                   (__attribute__((address_space(3))) void*)l, 16, 0, 0);
}

// ---------------- conversions ----------------

__global__ void cast_flat(const float* __restrict__ in, ushortT* __restrict__ outb) {
  size_t idx = (size_t)blockIdx.x * 256 + threadIdx.x;
  f32x4 v = *(const f32x4*)(in + idx * 4);
  ushort4v r;
  r[0] = f2bf(v[0]); r[1] = f2bf(v[1]); r[2] = f2bf(v[2]); r[3] = f2bf(v[3]);
  *(ushort4v*)(outb + idx * 4) = r;
}

// u (4,4096,512) f32 -> Upad (4,4098,512) bf16 rows shifted +1
__global__ void convert_u_pad(const float* __restrict__ in, ushortT* __restrict__ up) {
  size_t idx = (size_t)blockIdx.x * 256 + threadIdx.x;  // 2,097,152 quads
  f32x4 v = *(const f32x4*)(in + idx * 4);
  ushort4v r;
  r[0] = f2bf(v[0]); r[1] = f2bf(v[1]); r[2] = f2bf(v[2]); r[3] = f2bf(v[3]);
  size_t g = idx * 4;
  int col = (int)(g & 511);
  int l = (int)(g >> 9);
  int b = l >> 12;
  *(ushort4v*)(up + ((size_t)b * PADROWS + (l & 4095) + 1) * 512 + col) = r;
}

__global__ void zero_pad_u(ushortT* __restrict__ Upad) {
  int idx = blockIdx.x * 256 + threadIdx.x;   // 4096
  int col = idx & 511;
  int r = (idx >> 9) & 1;
  int b = idx >> 10;
  Upad[((size_t)b * PADROWS + (r ? 4097 : 0)) * 512 + col] = 0;
}

// cW (2048,2048,3) f32 -> Wt[h][o][i] bf16
__global__ void convert_cW(const float* __restrict__ cW, ushortT* __restrict__ Wt) {
  size_t idx = (size_t)blockIdx.x * 256 + threadIdx.x;
  const float* p = cW + idx * 3;
  Wt[idx]           = f2bf(p[0]);
  Wt[idx + 4194304] = f2bf(p[1]);
  Wt[idx + 8388608] = f2bf(p[2]);
}

__global__ void pbc_kernel(const float* __restrict__ cW, const float* __restrict__ pb,
                           const float* __restrict__ cb, float* __restrict__ biasC,
                           float* __restrict__ pbC0, float* __restrict__ pbC2) {
  int o = blockIdx.x;
  int tid = threadIdx.x;
  float s0 = 0.f, s1 = 0.f, s2 = 0.f;
  const float* base = cW + (size_t)o * 2048 * 3;
  for (int i = tid; i < 2048; i += 256) {
    float p = pb[i];
    s0 = fmaf(p, base[i * 3 + 0], s0);
    s1 = fmaf(p, base[i * 3 + 1], s1);
    s2 = fmaf(p, base[i * 3 + 2], s2);
  }
#pragma unroll
  for (int off = 32; off >= 1; off >>= 1) {
    s0 += __shfl_down(s0, off);
    s1 += __shfl_down(s1, off);
    s2 += __shfl_down(s2, off);
  }
  __shared__ float red[4][3];
  if ((tid & 63) == 0) { red[tid >> 6][0] = s0; red[tid >> 6][1] = s1; red[tid >> 6][2] = s2; }
  __syncthreads();
  if (tid == 0) {
    float a0 = red[0][0] + red[1][0] + red[2][0] + red[3][0];
    float a1 = red[0][1] + red[1][1] + red[2][1] + red[3][1];
    float a2 = red[0][2] + red[1][2] + red[2][2] + red[3][2];
    biasC[o] = cb[o] + a0 + a1 + a2;
    pbC0[o] = a0;
    pbC2[o] = a2;
  }
}

__global__ void pe_window(float* __restrict__ tT, float* __restrict__ window) {
  int idx = blockIdx.x * 256 + threadIdx.x;  // 262144
  int l = idx & 4095, d2 = idx >> 12;
  float dv = expf(-9.210340371976184f * (float)(2 * d2) / 128.0f);
  float ang = (float)l * dv;
  tT[(size_t)(2 * d2) * 4096 + l] = sinf(ang);
  tT[(size_t)(2 * d2 + 1) * 4096 + l] = cosf(ang);
  if (d2 == 0)
    window[l] = 0.5f * (1.0f - cosf(6.283185307179586f * (float)l / 4095.0f));
}

// master twiddle: Wg[m] = exp(-2*pi*i*m/2048)
__global__ void fill_wtab(float2* __restrict__ Wg) {
  int m = blockIdx.x * 256 + threadIdx.x;  // 2048
  float sn, cs;
  sincosf(-2.0f * PI_F * (float)m / 2048.0f, &sn, &cs);
  Wg[m] = make_float2(cs, sn);
}

// ---------------- fold GEMM: cWf[h][o][j] = sum_i Wt[h][o][i] * pW[j][i] ----------------

__launch_bounds__(256, 2)
__global__ void gemm_fold(const ushortT* __restrict__ Wt, const ushortT* __restrict__ pW_bf,
                          ushortT* __restrict__ cWf) {
  __shared__ alignas(16) ushortT As[128 * 64];
  __shared__ alignas(16) ushortT Bs[128 * 64];
  const int tid = threadIdx.x;
  const int lane = tid & 63, w = tid >> 6;
  const int wm = w >> 1, wn = w & 1;
  const int tm = blockIdx.x, tn = blockIdx.y, h = blockIdx.z;
  const ushortT* A = Wt + (size_t)h * 4194304;
  f32x4 acc[4][4] = {};
#pragma unroll 1
  for (int kt = 0; kt < 32; ++kt) {
    const int i0 = kt * 64;
#pragma unroll
    for (int i = 0; i < 4; ++i) {
      int ldsoff = (i * 4 + w) * 1024;
      int m = ((i * 4 + w) << 3) + (lane >> 3);
      int col = (lane & 7) * 8;
      gl2lds16(A + (size_t)(tm * 128 + m) * 2048 + i0 + col, (char*)As + ldsoff);
      gl2lds16(pW_bf + (size_t)(tn * 128 + m) * 2048 + i0 + col, (char*)Bs + ldsoff);
    }
    __syncthreads();
#pragma unroll
    for (int ks = 0; ks < 2; ++ks) {
      short8 av[4], bv[4];
#pragma unroll
      for (int mi = 0; mi < 4; ++mi) {
        int row = wm * 64 + mi * 16 + (lane & 15);
        av[mi] = *(const short8*)(As + row * 64 + (ks * 4 + (lane >> 4)) * 8);
      }
#pragma unroll
      for (int ni = 0; ni < 4; ++ni) {
        int row = wn * 64 + ni * 16 + (lane & 15);
        bv[ni] = *(const short8*)(Bs + row * 64 + (ks * 4 + (lane >> 4)) * 8);
      }
#pragma unroll
      for (int mi = 0; mi < 4; ++mi)
#pragma unroll
        for (int ni = 0; ni < 4; ++ni)
          acc[mi][ni] = __builtin_amdgcn_mfma_f32_16x16x32_bf16(av[mi], bv[ni], acc[mi][ni], 0, 0, 0);
    }
    __syncthreads();
  }
#pragma unroll
  for (int mi = 0; mi < 4; ++mi)
#pragma unroll
    for (int ni = 0; ni < 4; ++ni) {
      int jc = tn * 128 + wn * 64 + ni * 16 + (lane & 15);
#pragma unroll
      for (int j = 0; j < 4; ++j) {
        int o = tm * 128 + wm * 64 + mi * 16 + (lane >> 4) * 4 + j;
        cWf[((size_t)h * 2048 + o) * 512 + jc] = f2bf(acc[mi][ni][j]);
      }
    }
}

// ---------------- conv GEMM: 256x256 8-phase pipeline, K=1536 ----------------

__launch_bounds__(512, 2)
__global__ void gemm_conv8(const ushortT* __restrict__ Upad, const ushortT* __restrict__ cWf,
                           const float* __restrict__ biasC, const float* __restrict__ pbC0,
                           const float* __restrict__ pbC2, float* __restrict__ vT,
                           ushortT* __restrict__ projsT) {
  __shared__ ushortT lds[2][2][16384];
  const int tid = threadIdx.x;
  const int lane = tid & 63, w = tid >> 6;
  const int wm = w >> 2, wn = w & 3;
  int raw = blockIdx.x;
  int wg  = (raw & 7) * 64 + (raw >> 3);
  const int o0 = (wg >> 6) << 8;
  const int nt = wg & 63;
  const int b  = nt >> 4;
  const int l0 = (nt & 15) << 8;

  f32x4 acc[8][4] = {};
  short8 xf[4][2];

  const int sm = tid >> 3;
  const int sw1 = ((tid & 7) ^ (sm & 7)) << 3;

  auto stageW = [&](int slot, int half, int t) {
    int q = (t * 21846) >> 16, h = t - 3 * q, j0 = q << 6;
    size_t grow = (size_t)(h * 2048 + o0 + half * 128 + sm);
    char* dst = (char*)&lds[slot][0][0] + half * 16384 + w * 1024;
    gl2lds16(cWf + grow * 512 + j0 + sw1, dst);
    gl2lds16(cWf + (grow + 64) * 512 + j0 + sw1, dst + 8192);
  };
  auto stageX = [&](int slot, int half, int t) {
    int q = (t * 21846) >> 16, h = t - 3 * q, j0 = q << 6;
    size_t grow = (size_t)b * PADROWS + l0 + h + half * 128 + sm;
    char* dst = (char*)&lds[slot][1][0] + half * 16384 + w * 1024;
    gl2lds16(Upad + grow * 512 + j0 + sw1, dst);
    gl2lds16(Upad + (grow + 64) * 512 + j0 + sw1, dst + 8192);
  };
  auto ldsW = [&](int slot, int mi, int ks) -> short8 {
    int row = wm * 128 + mi * 16 + (lane & 15);
    int ch = (ks * 4 + (lane >> 4)) ^ (row & 7);
    return *(const short8*)&lds[slot][0][row * 64 + ch * 8];
  };
  auto ldsX = [&](int slot, int ni, int ks) -> short8 {
    int row = wn * 64 + ni * 16 + (lane & 15);
    int ch = (ks * 4 + (lane >> 4)) ^ (row & 7);
    return *(const short8*)&lds[slot][1][row * 64 + ch * 8];
  };

  stageW(0, 0, 0); stageW(0, 1, 0);
  stageX(0, 0, 0); stageX(0, 1, 0);
  stageX(1, 0, 1); stageX(1, 1, 1);
  asm volatile("s_waitcnt vmcnt(0)" ::: "memory");
  __builtin_amdgcn_s_barrier();

#define PHASE(slot, q, STAGECODE, VMCODE)                                                                    \
  {                                                                                                          \
    short8 w0k0 = ldsW(slot, 2*(q), 0), w0k1 = ldsW(slot, 2*(q), 1);                                         \
    short8 w1k0 = ldsW(slot, 2*(q)+1, 0), w1k1 = ldsW(slot, 2*(q)+1, 1);                                     \
    if ((q) == 0) {                                                                                          \
      _Pragma("unroll")                                                                                      \
      for (int ni = 0; ni < 4; ++ni) {                                                                       \
        xf[ni][0] = ldsX(slot, ni, 0);                                                                       \
        xf[ni][1] = ldsX(slot, ni, 1);                                                                       \
      }                                                                                                      \
    }                                                                                                        \
    STAGECODE;                                                                                               \
    VMCODE;                                                                                                  \
    __builtin_amdgcn_s_barrier();                                                                            \
    asm volatile("s_waitcnt lgkmcnt(0)" ::: "memory");                                                       \
    __builtin_amdgcn_sched_barrier(0);                                                                       \
    __builtin_amdgcn_s_setprio(1);                                                                           \
    _Pragma("unroll")                                                                                        \
    for (int ni = 0; ni < 4; ++ni) {                                                                         \
      acc[2*(q)][ni]   = __builtin_amdgcn_mfma_f32_16x16x32_bf16(w0k0, xf[ni][0], acc[2*(q)][ni], 0, 0, 0);  \
      acc[2*(q)][ni]   = __builtin_amdgcn_mfma_f32_16x16x32_bf16(w0k1, xf[ni][1], acc[2*(q)][ni], 0, 0, 0);  \
      acc[2*(q)+1][ni] = __builtin_amdgcn_mfma_f32_16x16x32_bf16(w1k0, xf[ni][0], acc[2*(q)+1][ni], 0, 0, 0);\
      acc[2*(q)+1][ni] = __builtin_amdgcn_mfma_f32_16x16x32_bf16(w1k1, xf[ni][1], acc[2*(q)+1][ni], 0, 0, 0);\
    }                                                                                                        \
    __builtin_amdgcn_s_setprio(0);                                                                           \
    __builtin_amdgcn_s_barrier();                                                                            \
  }

#pragma unroll 1
  for (int it = 0; it < 11; ++it) {
    const int t0 = 2 * it;
    PHASE(0, 0, stageW(1, 0, t0 + 1), );
    PHASE(0, 1, stageW(1, 1, t0 + 1), );
    PHASE(0, 2, stageX(0, 0, t0 + 2), );
    PHASE(0, 3, stageX(0, 1, t0 + 2), asm volatile("s_waitcnt vmcnt(4)" ::: "memory"));
    PHASE(1, 0, stageW(0, 0, t0 + 2), );
    PHASE(1, 1, stageW(0, 1, t0 + 2), );
    PHASE(1, 2, stageX(1, 0, t0 + 3), );
    PHASE(1, 3, stageX(1, 1, t0 + 3), asm volatile("s_waitcnt vmcnt(4)" ::: "memory"));
  }
  PHASE(0, 0, stageW(1, 0, 23), );
  PHASE(0, 1, stageW(1, 1, 23), );
  PHASE(0, 2, , );
  PHASE(0, 3, , asm volatile("s_waitcnt vmcnt(0)" ::: "memory"));
  PHASE(1, 0, , );
  PHASE(1, 1, , );
  PHASE(1, 2, , );
  PHASE(1, 3, , );
#undef PHASE

  const int r4 = (lane >> 4) * 4;
  const int lbase = l0 + wn * 64 + (lane & 15);
  if (o0 < 512) {
#pragma unroll
    for (int mi = 0; mi < 8; ++mi)
#pragma unroll
      for (int ni = 0; ni < 4; ++ni) {
        int l = lbase + ni * 16;
#pragma unroll
        for (int j = 0; j < 4; ++j) {
          int o = o0 + wm * 128 + mi * 16 + r4 + j;
          float val = acc[mi][ni][j] + biasC[o];
          if (l == 0) val -= pbC0[o];
          if (l == 4095) val -= pbC2[o];
          vT[((size_t)b * 512 + o) * 4096 + l] = val;
        }
      }
  } else {
#pragma unroll
    for (int mi = 0; mi < 8; ++mi)
#pragma unroll
      for (int ni = 0; ni < 4; ++ni) {
        int l = lbase + ni * 16;
#pragma unroll
        for (int j = 0; j < 4; ++j) {
          int o = o0 + wm * 128 + mi * 16 + r4 + j;
          float val = acc[mi][ni][j] + biasC[o];
          if (l == 0) val -= pbC0[o];
          if (l == 4095) val -= pbC2[o];
          int oc = o - 512;
          projsT[((size_t)((oc >> 9) * 4 + b) * 512 + (oc & 511)) * 4096 + l] = f2bf(val);
        }
      }
  }
}

// ---------------- filter GEMM: hT[ch][l] = (t @ fW + fb)*window ----------------

__launch_bounds__(256, 1)
__global__ void h_kernel(const float* __restrict__ tT, const float* __restrict__ fW,
                         const float* __restrict__ fb, const float* __restrict__ window,
                         float* __restrict__ hT) {
  __shared__ float tTs[128][64];
  __shared__ float fWs[128][128];
  const int l0 = blockIdx.x * 64;
  const int c0 = blockIdx.y * 128;
  const int tid = threadIdx.x;
  {
    int lq = (tid & 15) * 4;
    int dr = tid >> 4;
#pragma unroll
    for (int d = dr; d < 128; d += 16)
      *(f32x4*)(&tTs[d][lq]) = *(const f32x4*)(tT + (size_t)d * 4096 + l0 + lq);
  }
  {
    int cq = (tid & 31) * 4;
    int dr = tid >> 5;
#pragma unroll
    for (int d = dr; d < 128; d += 8)
      *(f32x4*)(&fWs[d][cq]) = *(const f32x4*)(fW + (size_t)d * 1536 + c0 + cq);
  }
  __syncthreads();
  const int lgrp = tid & 15;
  const int cg = tid >> 4;
  float acc[8][4] = {};
#pragma unroll 4
  for (int d = 0; d < 128; ++d) {
    f32x4 tv = *(const f32x4*)(&tTs[d][lgrp * 4]);
#pragma unroll
    for (int j = 0; j < 8; ++j) {
      float wv = fWs[d][cg + 16 * j];
      acc[j][0] = fmaf(tv[0], wv, acc[j][0]);
      acc[j][1] = fmaf(tv[1], wv, acc[j][1]);
      acc[j][2] = fmaf(tv[2], wv, acc[j][2]);
      acc[j][3] = fmaf(tv[3], wv, acc[j][3]);
    }
  }
  f32x4 wl = *(const f32x4*)(window + l0 + lgrp * 4);
#pragma unroll
  for (int j = 0; j < 8; ++j) {
    int ch = c0 + cg + 16 * j;
    float fbv = fb[ch];
    f32x4 r;
    r[0] = (acc[j][0] + fbv) * wl[0];
    r[1] = (acc[j][1] + fbv) * wl[1];
    r[2] = (acc[j][2] + fbv) * wl[2];
    r[3] = (acc[j][3] + fbv) * wl[3];
    *(f32x4*)(hT + (size_t)ch * 4096 + l0 + lgrp * 4) = r;
  }
}

// ---------------- radix-8 Stockham FFT, N=2048 complex, in-place in LDS ----------------

__device__ __forceinline__ float2 cadd(float2 a, float2 b){ return make_float2(a.x+b.x, a.y+b.y); }
__device__ __forceinline__ float2 csub(float2 a, float2 b){ return make_float2(a.x-b.x, a.y-b.y); }
__device__ __forceinline__ float2 cmulp(float2 a, float2 b){
  return make_float2(a.x*b.x - a.y*b.y, a.x*b.y + a.y*b.x);
}
template<bool INV>
__device__ __forceinline__ float2 tw_mul(float2 a, float2 w) {  // a*w (fwd) or a*conj(w) (inv)
  return INV ? make_float2(fmaf(a.x, w.x,  a.y*w.y), fmaf(a.y, w.x, -a.x*w.y))
             : make_float2(fmaf(a.x, w.x, -a.y*w.y), fmaf(a.x, w.y,  a.y*w.x));
}
template<bool INV>
__device__ __forceinline__ float2 rot(float2 z) {  // *(-i) fwd, *(+i) inv
  return INV ? make_float2(-z.y, z.x) : make_float2(z.y, -z.x);
}

template<bool INV, int NS>
__device__ __forceinline__ void stage_r8(float2* X, const float2* Wl, int t) {
  const float C7 = 0.70710678118654752f;
  float2 v[8];
#pragma unroll
  for (int r = 0; r < 8; ++r) v[r] = X[PHYS(t + 256 * r)];
  if (NS > 1) {
    const int jm = (t & (NS - 1)) * (256 / NS);
#pragma unroll
    for (int r = 1; r < 8; ++r) v[r] = tw_mul<INV>(v[r], Wl[PHYS(r * jm)]);
  }
  float2 a0 = cadd(v[0], v[4]), a1 = csub(v[0], v[4]);
  float2 a2 = cadd(v[2], v[6]), a3 = rot<INV>(csub(v[2], v[6]));
  float2 E0 = cadd(a0, a2), E1 = cadd(a1, a3), E2 = csub(a0, a2), E3 = csub(a1, a3);
  float2 b0 = cadd(v[1], v[5]), b1 = csub(v[1], v[5]);
  float2 b2 = cadd(v[3], v[7]), b3 = rot<INV>(csub(v[3], v[7]));
  float2 O0 = cadd(b0, b2), O1 = cadd(b1, b3), O2 = csub(b0, b2), O3 = csub(b1, b3);
  const float2 w1 = INV ? make_float2(C7, C7)  : make_float2(C7, -C7);
  const float2 w3 = INV ? make_float2(-C7, C7) : make_float2(-C7, -C7);
  O1 = cmulp(O1, w1);
  O2 = rot<INV>(O2);
  O3 = cmulp(O3, w3);
  __syncthreads();
  const int base = (t / NS) * (8 * NS) + (t % NS);
  X[PHYS(base)]          = cadd(E0, O0);
  X[PHYS(base + NS)]     = cadd(E1, O1);
  X[PHYS(base + 2*NS)]   = cadd(E2, O2);
  X[PHYS(base + 3*NS)]   = cadd(E3, O3);
  X[PHYS(base + 4*NS)]   = csub(E0, O0);
  X[PHYS(base + 5*NS)]   = csub(E1, O1);
  X[PHYS(base + 6*NS)]   = csub(E2, O2);
  X[PHYS(base + 7*NS)]   = csub(E3, O3);
  __syncthreads();
}

template<bool INV>
__device__ __forceinline__ void stage_r4(float2* X, const float2* Wl, int t) {
#pragma unroll
  for (int jj = 0; jj < 2; ++jj) {
    const int j = t + jj * 256;
    float2 v0 = X[PHYS(j)], v1 = X[PHYS(j + 512)], v2 = X[PHYS(j + 1024)], v3 = X[PHYS(j + 1536)];
    v1 = tw_mul<INV>(v1, Wl[PHYS(j)]);
    v2 = tw_mul<INV>(v2, Wl[PHYS(2 * j)]);
    v3 = tw_mul<INV>(v3, Wl[PHYS(3 * j)]);
    float2 a0 = cadd(v0, v2), a1 = csub(v0, v2), a2 = cadd(v1, v3), a3 = rot<INV>(csub(v1, v3));
    X[PHYS(j)]        = cadd(a0, a2);
    X[PHYS(j + 512)]  = cadd(a1, a3);
    X[PHYS(j + 1024)] = csub(a0, a2);
    X[PHYS(j + 1536)] = csub(a1, a3);
  }
  __syncthreads();
}

template<bool INV>
__device__ __forceinline__ void fft2048r8(float2* X, const float2* Wl, int t) {
  stage_r8<INV, 1>(X, Wl, t);
  stage_r8<INV, 8>(X, Wl, t);
  stage_r8<INV, 64>(X, Wl, t);
  stage_r4<INV>(X, Wl, t);
}

// filters: rfft(h) then fold into spectral-pass coefficients:
// W[k] = a1*Z[k] + b1*conj(Z[M-k]);  a1 = ((1-s)Hk + (1+s)conj(Hm))/2, b1 = (i c/2)(Hk - conj(Hm))
__launch_bounds__(256, 2)
__global__ void fft_filter_r(const float* __restrict__ hT, const float2* __restrict__ Wg,
                             float4* __restrict__ ABp) {
  __shared__ float2 X[2048];
  __shared__ float2 Wl[2048];
  __shared__ float2 H[2049];
  const int ch = blockIdx.x;
  const int tid = threadIdx.x;
  const float* sig = hT + (size_t)ch * 4096;
  for (int m = tid; m < 2048; m += 256) {
    Wl[PHYS(m)] = Wg[m];
    X[PHYS(m)] = *(const float2*)(sig + 2 * m);
  }
  __syncthreads();
  fft2048r8<false>(X, Wl, tid);
  for (int kk = tid; kk < 1024; kk += 256) {
    if (kk == 0) {
      float2 z0 = X[PHYS(0)];
      H[0]    = make_float2(z0.x + z0.y, 0.f);
      H[2048] = make_float2(z0.x - z0.y, 0.f);
      float2 zq = X[PHYS(1024)];
      H[1024] = make_float2(zq.x, -zq.y);
    } else {
      float2 zk = X[PHYS(kk)], zm = X[PHYS(2048 - kk)];
      float2 E = make_float2(0.5f * (zk.x + zm.x), 0.5f * (zk.y - zm.y));
      float2 D = make_float2(0.5f * (zk.x - zm.x), 0.5f * (zk.y + zm.y));
      float2 O = make_float2(D.y, -D.x);
      float sn, cs;
      __sincosf(-PI_F * (float)kk * (1.0f / 2048.0f), &sn, &cs);
      float2 twO = make_float2(O.x * cs - O.y * sn, O.x * sn + O.y * cs);
      H[kk]        = make_float2(E.x + twO.x, E.y + twO.y);
      H[2048 - kk] = make_float2(E.x - twO.x, -(E.y - twO.y));
    }
  }
  __syncthreads();
  float4* ab = ABp + ((size_t)ch << 11);
  for (int kk = tid; kk < 1024; kk += 256) {
    if (kk == 0) {
      float2 h0 = H[0], hM = H[2048], hq = H[1024];
      ab[0] = make_float4(0.5f * (h0.x + hM.x), 0.f, 0.f, 0.5f * (h0.x - hM.x));
      ab[1] = make_float4(hq.x, -hq.y, 0.f, 0.f);   // k=1024: a=conj(H), b=0
    } else {
      float2 hk = H[kk], hm = H[2048 - kk];
      float sn, cs;
      __sincosf(PI_F * (float)kk * (1.0f / 2048.0f), &sn, &cs);
      float oms = 0.5f * (1.f - sn), ops = 0.5f * (1.f + sn), ch2 = 0.5f * cs;
      float2 al1 = make_float2(oms * hk.x + ops * hm.x, oms * hk.y - ops * hm.y);
      float2 d1  = make_float2(hk.x - hm.x, hk.y + hm.y);
      float2 be1 = make_float2(-ch2 * d1.y, ch2 * d1.x);
      float2 al2 = make_float2(oms * hm.x + ops * hk.x, oms * hm.y - ops * hk.y);
      float2 d2  = make_float2(hm.x - hk.x, hm.y + hk.y);
      float2 be2 = make_float2(ch2 * d2.y, -ch2 * d2.x);
      ab[2 * kk]     = make_float4(al1.x, al1.y, be1.x, be1.y);
      ab[2 * kk + 1] = make_float4(al2.x, al2.y, be2.x, be2.y);
    }
  }
}

// all 3 Hyena orders fused; v stays in LDS; radix-8 FFTs + precomputed spectral coefs
__launch_bounds__(256, 4)
__global__ void fft_conv3(float* __restrict__ vT, const ushortT* __restrict__ projsT,
                          const float4* __restrict__ ABp, const float2* __restrict__ Wg) {
  __shared__ float2 X[2048];
  __shared__ float2 Wl[2048];
  const int bc = blockIdx.x;   // b*512 + c
  const int c = bc & 511, b = bc >> 9;
  const int tid = threadIdx.x;
  float* sig = vT + (size_t)bc * 4096;
  for (int m = tid; m < 2048; m += 256) {
    Wl[PHYS(m)] = Wg[m];
    X[PHYS(m)] = *(const float2*)(sig + 2 * m);
  }
  __syncthreads();
  fft2048r8<false>(X, Wl, tid);
  const float scale = 1.0f / 2048.0f;
#pragma unroll 1
  for (int k = 0; k < 3; ++k) {
    const float4* ab = ABp + ((size_t)(k * 512 + c) << 11);
    for (int kk = tid; kk < 1024; kk += 256) {
      float4 A1 = ab[2 * kk], A2 = ab[2 * kk + 1];
      int e2 = kk ? 2048 - kk : 1024;
      float2 Zk = X[PHYS(kk)], Zm = X[PHYS(e2)];
      float2 c1 = kk ? Zm : Zk;
      float2 c2 = kk ? Zk : Zm;
      float2 Wk, Wm;
      Wk.x = A1.x * Zk.x - A1.y * Zk.y + A1.z * c1.x + A1.w * c1.y;
      Wk.y = A1.x * Zk.y + A1.y * Zk.x - A1.z * c1.y + A1.w * c1.x;
      Wm.x = A2.x * Zm.x - A2.y * Zm.y + A2.z * c2.x + A2.w * c2.y;
      Wm.y = A2.x * Zm.y + A2.y * Zm.x - A2.z * c2.y + A2.w * c2.x;
      X[PHYS(kk)] = Wk;
      X[PHYS(e2)] = Wm;
    }
    __syncthreads();
    fft2048r8<true>(X, Wl, tid);
    const ushortT* xn = projsT + ((size_t)(k * 4 + b) * 512 + c) * 4096;
    if (k < 2) {
      for (int m = tid; m < 2048; m += 256) {
        unsigned int pr = *(const unsigned int*)(xn + 2 * m);
        float2 a = X[PHYS(m)];
        X[PHYS(m)] = make_float2(a.x * scale * bf2f((ushortT)(pr & 0xffffu)),
                                 a.y * scale * bf2f((ushortT)(pr >> 16)));
      }
      __syncthreads();
      fft2048r8<false>(X, Wl, tid);
    } else {
      for (int m = tid; m < 2048; m += 256) {
        unsigned int pr = *(const unsigned int*)(xn + 2 * m);
        float2 a = X[PHYS(m)];
        *(float2*)(sig + 2 * m) = make_float2(a.x * scale * bf2f((ushortT)(pr & 0xffffu)),
                                              a.y * scale * bf2f((ushortT)(pr >> 16)));
      }
    }
  }
}

// ---------------- output GEMM ----------------

__launch_bounds__(256)
__global__ void out_gemm(const float* __restrict__ vT, const float* __restrict__ oW,
                         const float* __restrict__ ob, float* __restrict__ out) {
  int l0 = blockIdx.x * 32;
  int b = l0 >> 12;
  int li = threadIdx.x & 31;
  int og = (threadIdx.x >> 5) * 4;
  float acc[4] = {};
  const float* vb = vT + (size_t)b * 512 * 4096 + (l0 & 4095) + li;
#pragma unroll 8
  for (int c = 0; c < 512; ++c) {
    float v = vb[(size_t)c * 4096];
#pragma unroll
    for (int j = 0; j < 4; ++j)
      acc[j] = fmaf(v, oW[c * 32 + og + j], acc[j]);
  }
  float* op = out + (size_t)(l0 + li) * 32 + og;
  f32x4 r;
  r[0] = acc[0] + ob[og];     r[1] = acc[1] + ob[og + 1];
  r[2] = acc[2] + ob[og + 2]; r[3] = acc[3] + ob[og + 3];
  *(f32x4*)op = r;
}

// ---------------- diagnostics ----------------

__global__ void ws_sentinel(float* __restrict__ out) {
  if (threadIdx.x == 0) out[0] = -31337.0f;
}

// ---------------- launch ----------------

extern "C" void kernel_launch(void* const* d_in, const int* in_sizes, int n_in,
                              void* d_out, int out_size, void* d_ws, size_t ws_size,
                              hipStream_t stream) {
  (void)in_sizes; (void)n_in; (void)out_size;
  const float* u  = (const float*)d_in[0];
  const float* pW = (const float*)d_in[1];
  const float* pb = (const float*)d_in[2];
  const float* cW = (const float*)d_in[3];
  const float* cb = (const float*)d_in[4];
  const float* fW = (const float*)d_in[5];
  const float* fb = (const float*)d_in[6];
  const float* oW = (const float*)d_in[7];
  const float* ob = (const float*)d_in[8];
  float* out = (float*)d_out;

  char* ws = (char*)d_ws;
  // persistent region
  ushortT* Upad   = (ushortT*)(ws);                    // 16,785,408
  ushortT* cWf    = (ushortT*)(ws + 16785408);         //  6,291,456
  float*   biasC  = (float*)  (ws + 23076864);         //      8,192
  float*   pbC0   = (float*)  (ws + 23085056);         //      8,192
  float*   pbC2   = (float*)  (ws + 23093248);         //      8,192
  float2*  Wg     = (float2*) (ws + 23101440);         //     16,384
  float4*  ABp    = (float4*) (ws + 23117824);         // 50,331,648  (1536 x 1024 x 32B)
  float*   vT     = (float*)  (ws + 73449472);         // 33,554,432
  ushortT* projsT = (ushortT*)(ws + 107003904);        // 50,331,648
  const size_t total = 157335552;                      // 150.0 MiB
  // scratch overlay on [vT, end) — all dead before gemm_conv8 writes vT/projsT
  char* S = (char*)vT;
  ushortT* Wt     = (ushortT*)(S);                     // 25,165,824
  ushortT* pW_bf  = (ushortT*)(S + 25165824);          //  2,097,152
  float*   tT     = (float*)  (S + 27262976);          //  2,097,152
  float*   window = (float*)  (S + 29360128);          //     16,384
  float*   hT     = (float*)  (S + 29376512);          // 25,165,824 -> ends 54,542,336

  if (total > ws_size) {
    ws_sentinel<<<1, 64, 0, stream>>>(out);
    return;
  }

  convert_u_pad<<<8192, 256, 0, stream>>>(u, Upad);
  zero_pad_u<<<16, 256, 0, stream>>>(Upad);
  cast_flat<<<1024, 256, 0, stream>>>(pW, pW_bf);
  convert_cW<<<16384, 256, 0, stream>>>(cW, Wt);
  pbc_kernel<<<2048, 256, 0, stream>>>(cW, pb, cb, biasC, pbC0, pbC2);
  gemm_fold<<<dim3(16, 4, 3), 256, 0, stream>>>(Wt, pW_bf, cWf);
  pe_window<<<1024, 256, 0, stream>>>(tT, window);
  fill_wtab<<<8, 256, 0, stream>>>(Wg);
  h_kernel<<<dim3(64, 12), 256, 0, stream>>>(tT, fW, fb, window, hT);
  fft_filter_r<<<1536, 256, 0, stream>>>(hT, Wg, ABp);
  gemm_conv8<<<512, 512, 0, stream>>>(Upad, cWf, biasC, pbC0, pbC2, vT, projsT);
  fft_conv3<<<2048, 256, 0, stream>>>(vT, projsT, ABp, Wg);
  out_gemm<<<512, 256, 0, stream>>>(vT, oW, ob, out);
}

// Round 8
// 318.844 us; speedup vs baseline: 12.0373x; 1.1066x over previous
//
#include <hip/hip_runtime.h>

typedef __attribute__((ext_vector_type(8))) short short8;
typedef __attribute__((ext_vector_type(4))) float f32x4;
typedef __attribute__((ext_vector_type(4))) unsigned short ushort4v;
typedef unsigned short ushortT;

#define PADROWS 4098
#define HSTR 2056
#define PI_F 3.14159265358979323f
#define PHYS(i) ((i) ^ (((i) >> 4) & 15))

__device__ __forceinline__ ushortT f2bf(float f) {
  union { float f; unsigned int u; } v; v.f = f;
  unsigned int r = (v.u + 0x7FFFu + ((v.u >> 16) & 1u)) >> 16;
  return (ushortT)r;
}
__device__ __forceinline__ float bf2f(ushortT b) {
  union { unsigned int u; float f; } v; v.u = ((unsigned int)b) << 16;
  return v.f;
}

__device__ __forceinline__ void gl2lds16(const void* g, void* l) {
  __builtin_amdgcn_global_load_lds((const __attribute__((address_space(1))) void*)g,
                                   (__attribute__((address_space(3))) void*)l, 16, 0, 0);
}

// ---------------- conversions ----------------

__global__ void cast_flat(const float* __restrict__ in, ushortT* __restrict__ outb) {
  size_t idx = (size_t)blockIdx.x * 256 + threadIdx.x;
  f32x4 v = *(const f32x4*)(in + idx * 4);
  ushort4v r;
  r[0] = f2bf(v[0]); r[1] = f2bf(v[1]); r[2] = f2bf(v[2]); r[3] = f2bf(v[3]);
  *(ushort4v*)(outb + idx * 4) = r;
}

// u (4,4096,512) f32 -> Upad (4,4098,512) bf16 rows shifted +1; blocks >= 8192 zero the pad rows
__global__ void convert_u_pad(const float* __restrict__ in, ushortT* __restrict__ up) {
  int blk = blockIdx.x;
  if (blk >= 8192) {
    int idx = (blk - 8192) * 256 + threadIdx.x;   // 4096
    int col = idx & 511;
    int r = (idx >> 9) & 1;
    int b = idx >> 10;
    up[((size_t)b * PADROWS + (r ? 4097 : 0)) * 512 + col] = 0;
    return;
  }
  size_t idx = (size_t)blk * 256 + threadIdx.x;
  f32x4 v = *(const f32x4*)(in + idx * 4);
  ushort4v r;
  r[0] = f2bf(v[0]); r[1] = f2bf(v[1]); r[2] = f2bf(v[2]); r[3] = f2bf(v[3]);
  size_t g = idx * 4;
  int col = (int)(g & 511);
  int l = (int)(g >> 9);
  int b = l >> 12;
  *(ushort4v*)(up + ((size_t)b * PADROWS + (l & 4095) + 1) * 512 + col) = r;
}

// fused: cW f32 -> Wt[h][o][i] bf16  AND  pbC reductions (single 50 MB pass)
__global__ void cwt_pbc(const float* __restrict__ cW, const float* __restrict__ pb,
                        const float* __restrict__ cb, ushortT* __restrict__ Wt,
                        float* __restrict__ biasC, float* __restrict__ pbC0,
                        float* __restrict__ pbC2) {
  int o = blockIdx.x;
  int tid = threadIdx.x;
  float s0 = 0.f, s1 = 0.f, s2 = 0.f;
  const float* base = cW + (size_t)o * 6144;
  for (int i = tid; i < 2048; i += 256) {
    float w0 = base[i * 3], w1 = base[i * 3 + 1], w2 = base[i * 3 + 2];
    size_t oi = (size_t)o * 2048 + i;
    Wt[oi]           = f2bf(w0);
    Wt[oi + 4194304] = f2bf(w1);
    Wt[oi + 8388608] = f2bf(w2);
    float p = pb[i];
    s0 = fmaf(p, w0, s0);
    s1 = fmaf(p, w1, s1);
    s2 = fmaf(p, w2, s2);
  }
#pragma unroll
  for (int off = 32; off >= 1; off >>= 1) {
    s0 += __shfl_down(s0, off);
    s1 += __shfl_down(s1, off);
    s2 += __shfl_down(s2, off);
  }
  __shared__ float red[4][3];
  if ((tid & 63) == 0) { red[tid >> 6][0] = s0; red[tid >> 6][1] = s1; red[tid >> 6][2] = s2; }
  __syncthreads();
  if (tid == 0) {
    float a0 = red[0][0] + red[1][0] + red[2][0] + red[3][0];
    float a1 = red[0][1] + red[1][1] + red[2][1] + red[3][1];
    float a2 = red[0][2] + red[1][2] + red[2][2] + red[3][2];
    biasC[o] = cb[o] + a0 + a1 + a2;
    pbC0[o] = a0;
    pbC2[o] = a2;
  }
}

// Wg[m] = exp(-2*pi*i*m/2048)  (m<2048);  Sg[k] = (cos,sin)(pi*k/2048) (k<1024)
__global__ void fill_tabs(float2* __restrict__ Wg, float2* __restrict__ Sg) {
  int m = blockIdx.x * 256 + threadIdx.x;  // 3072
  float sn, cs;
  if (m < 2048) {
    sincosf(-2.0f * PI_F * (float)m / 2048.0f, &sn, &cs);
    Wg[m] = make_float2(cs, sn);
  } else {
    int k = m - 2048;
    sincosf(PI_F * (float)k / 2048.0f, &sn, &cs);
    Sg[k] = make_float2(cs, sn);
  }
}

// ---------------- fold GEMM: cWf[h][o][j] = sum_i Wt[h][o][i] * pW[j][i] ----------------

__launch_bounds__(256, 2)
__global__ void gemm_fold(const ushortT* __restrict__ Wt, const ushortT* __restrict__ pW_bf,
                          ushortT* __restrict__ cWf) {
  __shared__ alignas(16) ushortT As[128 * 64];
  __shared__ alignas(16) ushortT Bs[128 * 64];
  const int tid = threadIdx.x;
  const int lane = tid & 63, w = tid >> 6;
  const int wm = w >> 1, wn = w & 1;
  const int tm = blockIdx.x, tn = blockIdx.y, h = blockIdx.z;
  const ushortT* A = Wt + (size_t)h * 4194304;
  f32x4 acc[4][4] = {};
#pragma unroll 1
  for (int kt = 0; kt < 32; ++kt) {
    const int i0 = kt * 64;
#pragma unroll
    for (int i = 0; i < 4; ++i) {
      int ldsoff = (i * 4 + w) * 1024;
      int m = ((i * 4 + w) << 3) + (lane >> 3);
      int col = (lane & 7) * 8;
      gl2lds16(A + (size_t)(tm * 128 + m) * 2048 + i0 + col, (char*)As + ldsoff);
      gl2lds16(pW_bf + (size_t)(tn * 128 + m) * 2048 + i0 + col, (char*)Bs + ldsoff);
    }
    __syncthreads();
#pragma unroll
    for (int ks = 0; ks < 2; ++ks) {
      short8 av[4], bv[4];
#pragma unroll
      for (int mi = 0; mi < 4; ++mi) {
        int row = wm * 64 + mi * 16 + (lane & 15);
        av[mi] = *(const short8*)(As + row * 64 + (ks * 4 + (lane >> 4)) * 8);
      }
#pragma unroll
      for (int ni = 0; ni < 4; ++ni) {
        int row = wn * 64 + ni * 16 + (lane & 15);
        bv[ni] = *(const short8*)(Bs + row * 64 + (ks * 4 + (lane >> 4)) * 8);
      }
#pragma unroll
      for (int mi = 0; mi < 4; ++mi)
#pragma unroll
        for (int ni = 0; ni < 4; ++ni)
          acc[mi][ni] = __builtin_amdgcn_mfma_f32_16x16x32_bf16(av[mi], bv[ni], acc[mi][ni], 0, 0, 0);
    }
    __syncthreads();
  }
#pragma unroll
  for (int mi = 0; mi < 4; ++mi)
#pragma unroll
    for (int ni = 0; ni < 4; ++ni) {
      int jc = tn * 128 + wn * 64 + ni * 16 + (lane & 15);
#pragma unroll
      for (int j = 0; j < 4; ++j) {
        int o = tm * 128 + wm * 64 + mi * 16 + (lane >> 4) * 4 + j;
        cWf[((size_t)h * 2048 + o) * 512 + jc] = f2bf(acc[mi][ni][j]);
      }
    }
}

// ---------------- conv GEMM: 256x256 8-phase pipeline, K=1536 ----------------

__launch_bounds__(512, 2)
__global__ void gemm_conv8(const ushortT* __restrict__ Upad, const ushortT* __restrict__ cWf,
                           const float* __restrict__ biasC, const float* __restrict__ pbC0,
                           const float* __restrict__ pbC2, float* __restrict__ vT,
                           ushortT* __restrict__ projsT) {
  __shared__ ushortT lds[2][2][16384];
  const int tid = threadIdx.x;
  const int lane = tid & 63, w = tid >> 6;
  const int wm = w >> 2, wn = w & 3;
  int raw = blockIdx.x;
  int wg  = (raw & 7) * 64 + (raw >> 3);
  const int o0 = (wg >> 6) << 8;
  const int nt = wg & 63;
  const int b  = nt >> 4;
  const int l0 = (nt & 15) << 8;

  f32x4 acc[8][4] = {};
  short8 xf[4][2];

  const int sm = tid >> 3;
  const int sw1 = ((tid & 7) ^ (sm & 7)) << 3;

  auto stageW = [&](int slot, int half, int t) {
    int q = (t * 21846) >> 16, h = t - 3 * q, j0 = q << 6;
    size_t grow = (size_t)(h * 2048 + o0 + half * 128 + sm);
    char* dst = (char*)&lds[slot][0][0] + half * 16384 + w * 1024;
    gl2lds16(cWf + grow * 512 + j0 + sw1, dst);
    gl2lds16(cWf + (grow + 64) * 512 + j0 + sw1, dst + 8192);
  };
  auto stageX = [&](int slot, int half, int t) {
    int q = (t * 21846) >> 16, h = t - 3 * q, j0 = q << 6;
    size_t grow = (size_t)b * PADROWS + l0 + h + half * 128 + sm;
    char* dst = (char*)&lds[slot][1][0] + half * 16384 + w * 1024;
    gl2lds16(Upad + grow * 512 + j0 + sw1, dst);
    gl2lds16(Upad + (grow + 64) * 512 + j0 + sw1, dst + 8192);
  };
  auto ldsW = [&](int slot, int mi, int ks) -> short8 {
    int row = wm * 128 + mi * 16 + (lane & 15);
    int ch = (ks * 4 + (lane >> 4)) ^ (row & 7);
    return *(const short8*)&lds[slot][0][row * 64 + ch * 8];
  };
  auto ldsX = [&](int slot, int ni, int ks) -> short8 {
    int row = wn * 64 + ni * 16 + (lane & 15);
    int ch = (ks * 4 + (lane >> 4)) ^ (row & 7);
    return *(const short8*)&lds[slot][1][row * 64 + ch * 8];
  };

  stageW(0, 0, 0); stageW(0, 1, 0);
  stageX(0, 0, 0); stageX(0, 1, 0);
  stageX(1, 0, 1); stageX(1, 1, 1);
  asm volatile("s_waitcnt vmcnt(0)" ::: "memory");
  __builtin_amdgcn_s_barrier();

#define PHASE(slot, q, STAGECODE, VMCODE)                                                                    \
  {                                                                                                          \
    short8 w0k0 = ldsW(slot, 2*(q), 0), w0k1 = ldsW(slot, 2*(q), 1);                                         \
    short8 w1k0 = ldsW(slot, 2*(q)+1, 0), w1k1 = ldsW(slot, 2*(q)+1, 1);                                     \
    if ((q) == 0) {                                                                                          \
      _Pragma("unroll")                                                                                      \
      for (int ni = 0; ni < 4; ++ni) {                                                                       \
        xf[ni][0] = ldsX(slot, ni, 0);                                                                       \
        xf[ni][1] = ldsX(slot, ni, 1);                                                                       \
      }                                                                                                      \
    }                                                                                                        \
    STAGECODE;                                                                                               \
    VMCODE;                                                                                                  \
    __builtin_amdgcn_s_barrier();                                                                            \
    asm volatile("s_waitcnt lgkmcnt(0)" ::: "memory");                                                       \
    __builtin_amdgcn_sched_barrier(0);                                                                       \
    __builtin_amdgcn_s_setprio(1);                                                                           \
    _Pragma("unroll")                                                                                        \
    for (int ni = 0; ni < 4; ++ni) {                                                                         \
      acc[2*(q)][ni]   = __builtin_amdgcn_mfma_f32_16x16x32_bf16(w0k0, xf[ni][0], acc[2*(q)][ni], 0, 0, 0);  \
      acc[2*(q)][ni]   = __builtin_amdgcn_mfma_f32_16x16x32_bf16(w0k1, xf[ni][1], acc[2*(q)][ni], 0, 0, 0);  \
      acc[2*(q)+1][ni] = __builtin_amdgcn_mfma_f32_16x16x32_bf16(w1k0, xf[ni][0], acc[2*(q)+1][ni], 0, 0, 0);\
      acc[2*(q)+1][ni] = __builtin_amdgcn_mfma_f32_16x16x32_bf16(w1k1, xf[ni][1], acc[2*(q)+1][ni], 0, 0, 0);\
    }                                                                                                        \
    __builtin_amdgcn_s_setprio(0);                                                                           \
    __builtin_amdgcn_s_barrier();                                                                            \
  }

#pragma unroll 1
  for (int it = 0; it < 11; ++it) {
    const int t0 = 2 * it;
    PHASE(0, 0, stageW(1, 0, t0 + 1), );
    PHASE(0, 1, stageW(1, 1, t0 + 1), );
    PHASE(0, 2, stageX(0, 0, t0 + 2), );
    PHASE(0, 3, stageX(0, 1, t0 + 2), asm volatile("s_waitcnt vmcnt(4)" ::: "memory"));
    PHASE(1, 0, stageW(0, 0, t0 + 2), );
    PHASE(1, 1, stageW(0, 1, t0 + 2), );
    PHASE(1, 2, stageX(1, 0, t0 + 3), );
    PHASE(1, 3, stageX(1, 1, t0 + 3), asm volatile("s_waitcnt vmcnt(4)" ::: "memory"));
  }
  PHASE(0, 0, stageW(1, 0, 23), );
  PHASE(0, 1, stageW(1, 1, 23), );
  PHASE(0, 2, , );
  PHASE(0, 3, , asm volatile("s_waitcnt vmcnt(0)" ::: "memory"));
  PHASE(1, 0, , );
  PHASE(1, 1, , );
  PHASE(1, 2, , );
  PHASE(1, 3, , );
#undef PHASE

  const int r4 = (lane >> 4) * 4;
  const int lbase = l0 + wn * 64 + (lane & 15);
  if (o0 < 512) {
#pragma unroll
    for (int mi = 0; mi < 8; ++mi)
#pragma unroll
      for (int ni = 0; ni < 4; ++ni) {
        int l = lbase + ni * 16;
#pragma unroll
        for (int j = 0; j < 4; ++j) {
          int o = o0 + wm * 128 + mi * 16 + r4 + j;
          float val = acc[mi][ni][j] + biasC[o];
          if (l == 0) val -= pbC0[o];
          if (l == 4095) val -= pbC2[o];
          vT[((size_t)b * 512 + o) * 4096 + l] = val;
        }
      }
  } else {
#pragma unroll
    for (int mi = 0; mi < 8; ++mi)
#pragma unroll
      for (int ni = 0; ni < 4; ++ni) {
        int l = lbase + ni * 16;
#pragma unroll
        for (int j = 0; j < 4; ++j) {
          int o = o0 + wm * 128 + mi * 16 + r4 + j;
          float val = acc[mi][ni][j] + biasC[o];
          if (l == 0) val -= pbC0[o];
          if (l == 4095) val -= pbC2[o];
          int oc = o - 512;
          projsT[((size_t)((oc >> 9) * 4 + b) * 512 + (oc & 511)) * 4096 + l] = f2bf(val);
        }
      }
  }
}

// ---------------- filter GEMM: hT[ch][l] = (t @ fW + fb)*window, PE computed in-kernel ----------------

__launch_bounds__(256, 1)
__global__ void h_kernel(const float* __restrict__ fW, const float* __restrict__ fb,
                         float* __restrict__ hT) {
  __shared__ float tTs[128][64];
  __shared__ float fWs[128][128];
  const int l0 = blockIdx.x * 64;
  const int c0 = blockIdx.y * 128;
  const int tid = threadIdx.x;
  // positional-encoding tile computed in place (identical formulas to reference)
  for (int r = tid; r < 4096; r += 256) {
    int d2 = r >> 6, li = r & 63;
    float dv = expf(-9.210340371976184f * (float)(2 * d2) / 128.0f);
    float ang = (float)(l0 + li) * dv;
    tTs[2 * d2][li] = sinf(ang);
    tTs[2 * d2 + 1][li] = cosf(ang);
  }
  {
    int cq = (tid & 31) * 4;
    int dr = tid >> 5;
#pragma unroll
    for (int d = dr; d < 128; d += 8)
      *(f32x4*)(&fWs[d][cq]) = *(const f32x4*)(fW + (size_t)d * 1536 + c0 + cq);
  }
  __syncthreads();
  const int lgrp = tid & 15;
  const int cg = tid >> 4;
  float acc[8][4] = {};
#pragma unroll 4
  for (int d = 0; d < 128; ++d) {
    f32x4 tv = *(const f32x4*)(&tTs[d][lgrp * 4]);
#pragma unroll
    for (int j = 0; j < 8; ++j) {
      float wv = fWs[d][cg + 16 * j];
      acc[j][0] = fmaf(tv[0], wv, acc[j][0]);
      acc[j][1] = fmaf(tv[1], wv, acc[j][1]);
      acc[j][2] = fmaf(tv[2], wv, acc[j][2]);
      acc[j][3] = fmaf(tv[3], wv, acc[j][3]);
    }
  }
  f32x4 wl;
#pragma unroll
  for (int j = 0; j < 4; ++j) {
    int l = l0 + lgrp * 4 + j;
    wl[j] = 0.5f * (1.0f - cosf(6.283185307179586f * (float)l / 4095.0f));
  }
#pragma unroll
  for (int j = 0; j < 8; ++j) {
    int ch = c0 + cg + 16 * j;
    float fbv = fb[ch];
    f32x4 r;
    r[0] = (acc[j][0] + fbv) * wl[0];
    r[1] = (acc[j][1] + fbv) * wl[1];
    r[2] = (acc[j][2] + fbv) * wl[2];
    r[3] = (acc[j][3] + fbv) * wl[3];
    *(f32x4*)(hT + (size_t)ch * 4096 + l0 + lgrp * 4) = r;
  }
}

// ---------------- radix-8 Stockham FFT, N=2048 complex, in-place in LDS ----------------

__device__ __forceinline__ float2 cadd(float2 a, float2 b){ return make_float2(a.x+b.x, a.y+b.y); }
__device__ __forceinline__ float2 csub(float2 a, float2 b){ return make_float2(a.x-b.x, a.y-b.y); }
__device__ __forceinline__ float2 cmulp(float2 a, float2 b){
  return make_float2(a.x*b.x - a.y*b.y, a.x*b.y + a.y*b.x);
}
template<bool INV>
__device__ __forceinline__ float2 tw_mul(float2 a, float2 w) {
  return INV ? make_float2(fmaf(a.x, w.x,  a.y*w.y), fmaf(a.y, w.x, -a.x*w.y))
             : make_float2(fmaf(a.x, w.x, -a.y*w.y), fmaf(a.x, w.y,  a.y*w.x));
}
template<bool INV>
__device__ __forceinline__ float2 rot(float2 z) {
  return INV ? make_float2(-z.y, z.x) : make_float2(z.y, -z.x);
}

template<bool INV, int NS>
__device__ __forceinline__ void stage_r8(float2* X, const float2* Wl, int t) {
  const float C7 = 0.70710678118654752f;
  float2 v[8];
#pragma unroll
  for (int r = 0; r < 8; ++r) v[r] = X[PHYS(t + 256 * r)];
  if (NS > 1) {
    const int jm = (t & (NS - 1)) * (256 / NS);
#pragma unroll
    for (int r = 1; r < 8; ++r) v[r] = tw_mul<INV>(v[r], Wl[PHYS(r * jm)]);
  }
  float2 a0 = cadd(v[0], v[4]), a1 = csub(v[0], v[4]);
  float2 a2 = cadd(v[2], v[6]), a3 = rot<INV>(csub(v[2], v[6]));
  float2 E0 = cadd(a0, a2), E1 = cadd(a1, a3), E2 = csub(a0, a2), E3 = csub(a1, a3);
  float2 b0 = cadd(v[1], v[5]), b1 = csub(v[1], v[5]);
  float2 b2 = cadd(v[3], v[7]), b3 = rot<INV>(csub(v[3], v[7]));
  float2 O0 = cadd(b0, b2), O1 = cadd(b1, b3), O2 = csub(b0, b2), O3 = csub(b1, b3);
  const float2 w1 = INV ? make_float2(C7, C7)  : make_float2(C7, -C7);
  const float2 w3 = INV ? make_float2(-C7, C7) : make_float2(-C7, -C7);
  O1 = cmulp(O1, w1);
  O2 = rot<INV>(O2);
  O3 = cmulp(O3, w3);
  __syncthreads();
  const int base = (t / NS) * (8 * NS) + (t % NS);
  X[PHYS(base)]          = cadd(E0, O0);
  X[PHYS(base + NS)]     = cadd(E1, O1);
  X[PHYS(base + 2*NS)]   = cadd(E2, O2);
  X[PHYS(base + 3*NS)]   = cadd(E3, O3);
  X[PHYS(base + 4*NS)]   = csub(E0, O0);
  X[PHYS(base + 5*NS)]   = csub(E1, O1);
  X[PHYS(base + 6*NS)]   = csub(E2, O2);
  X[PHYS(base + 7*NS)]   = csub(E3, O3);
  __syncthreads();
}

template<bool INV>
__device__ __forceinline__ void stage_r4(float2* X, const float2* Wl, int t) {
#pragma unroll
  for (int jj = 0; jj < 2; ++jj) {
    const int j = t + jj * 256;
    float2 v0 = X[PHYS(j)], v1 = X[PHYS(j + 512)], v2 = X[PHYS(j + 1024)], v3 = X[PHYS(j + 1536)];
    v1 = tw_mul<INV>(v1, Wl[PHYS(j)]);
    v2 = tw_mul<INV>(v2, Wl[PHYS(2 * j)]);
    v3 = tw_mul<INV>(v3, Wl[PHYS(3 * j)]);
    float2 a0 = cadd(v0, v2), a1 = csub(v0, v2), a2 = cadd(v1, v3), a3 = rot<INV>(csub(v1, v3));
    X[PHYS(j)]        = cadd(a0, a2);
    X[PHYS(j + 512)]  = cadd(a1, a3);
    X[PHYS(j + 1024)] = csub(a0, a2);
    X[PHYS(j + 1536)] = csub(a1, a3);
  }
  __syncthreads();
}

template<bool INV>
__device__ __forceinline__ void fft2048r8(float2* X, const float2* Wl, int t) {
  stage_r8<INV, 1>(X, Wl, t);
  stage_r8<INV, 8>(X, Wl, t);
  stage_r8<INV, 64>(X, Wl, t);
  stage_r4<INV>(X, Wl, t);
}

// filters: rfft of hT rows -> half-spectrum Hf[ch][0..2048]
__launch_bounds__(256, 4)
__global__ void fft_filter_r(const float* __restrict__ hT, const float2* __restrict__ Wg,
                             float2* __restrict__ Hf) {
  __shared__ float2 X[2048];
  __shared__ float2 Wl[2048];
  const int ch = blockIdx.x;
  const int tid = threadIdx.x;
  const float* sig = hT + (size_t)ch * 4096;
  for (int m = tid; m < 2048; m += 256) {
    Wl[PHYS(m)] = Wg[m];
    X[PHYS(m)] = *(const float2*)(sig + 2 * m);
  }
  __syncthreads();
  fft2048r8<false>(X, Wl, tid);
  float2* o = Hf + (size_t)ch * HSTR;
  for (int kk = tid; kk < 1024; kk += 256) {
    if (kk == 0) {
      float2 z0 = X[PHYS(0)];
      o[0]    = make_float2(z0.x + z0.y, 0.f);
      o[2048] = make_float2(z0.x - z0.y, 0.f);
      float2 zq = X[PHYS(1024)];
      o[1024] = make_float2(zq.x, -zq.y);
    } else {
      float2 zk = X[PHYS(kk)], zm = X[PHYS(2048 - kk)];
      float2 E = make_float2(0.5f * (zk.x + zm.x), 0.5f * (zk.y - zm.y));
      float2 D = make_float2(0.5f * (zk.x - zm.x), 0.5f * (zk.y + zm.y));
      float2 O = make_float2(D.y, -D.x);
      float sn, cs;
      __sincosf(-PI_F * (float)kk * (1.0f / 2048.0f), &sn, &cs);
      float2 twO = make_float2(O.x * cs - O.y * sn, O.x * sn + O.y * cs);
      o[kk]        = make_float2(E.x + twO.x, E.y + twO.y);
      o[2048 - kk] = make_float2(E.x - twO.x, -(E.y - twO.y));
    }
  }
}

// all 3 Hyena orders fused; gate coefficients computed from Hf + S-table (no ABp)
__launch_bounds__(256, 4)
__global__ void fft_conv3(float* __restrict__ vT, const ushortT* __restrict__ projsT,
                          const float2* __restrict__ Hf, const float2* __restrict__ Wg,
                          const float2* __restrict__ Sg) {
  __shared__ float2 X[2048];
  __shared__ float2 Wl[2048];
  __shared__ float2 S[1024];
  const int bc = blockIdx.x;   // b*512 + c
  const int c = bc & 511, b = bc >> 9;
  const int tid = threadIdx.x;
  float* sig = vT + (size_t)bc * 4096;
  for (int m = tid; m < 2048; m += 256) {
    Wl[PHYS(m)] = Wg[m];
    X[PHYS(m)] = *(const float2*)(sig + 2 * m);
  }
  for (int m = tid; m < 1024; m += 256) S[m] = Sg[m];
  __syncthreads();
  fft2048r8<false>(X, Wl, tid);
  const float scale = 1.0f / 2048.0f;
#pragma unroll 1
  for (int k = 0; k < 3; ++k) {
    const float2* H = Hf + (size_t)(k * 512 + c) * HSTR;
    for (int kk = tid; kk < 1024; kk += 256) {
      if (kk == 0) {
        float h0x = H[0].x, hMx = H[2048].x;
        float2 hq = H[1024];
        float a1r = 0.5f * (h0x + hMx), a1w = 0.5f * (h0x - hMx);
        float2 Z0 = X[PHYS(0)], Zq = X[PHYS(1024)];
        X[PHYS(0)]    = make_float2(a1r * Z0.x + a1w * Z0.y, a1r * Z0.y + a1w * Z0.x);
        X[PHYS(1024)] = make_float2(hq.x * Zq.x + hq.y * Zq.y, hq.x * Zq.y - hq.y * Zq.x);
      } else {
        float2 hk = H[kk], hm = H[2048 - kk];
        float cs = S[kk].x, sn = S[kk].y;
        float oms = 0.5f * (1.f - sn), ops = 0.5f * (1.f + sn), c2h = 0.5f * cs;
        float d1x = hk.x - hm.x, d1y = hk.y + hm.y;
        float a1x = oms * hk.x + ops * hm.x, a1y = oms * hk.y - ops * hm.y;
        float b1x = -c2h * d1y, b1y = c2h * d1x;
        float a2x = oms * hm.x + ops * hk.x, a2y = oms * hm.y - ops * hk.y;
        float b2x = c2h * d1y, b2y = c2h * d1x;
        float2 Zk = X[PHYS(kk)], Zm = X[PHYS(2048 - kk)];
        X[PHYS(kk)] = make_float2(a1x * Zk.x - a1y * Zk.y + b1x * Zm.x + b1y * Zm.y,
                                  a1x * Zk.y + a1y * Zk.x - b1x * Zm.y + b1y * Zm.x);
        X[PHYS(2048 - kk)] = make_float2(a2x * Zm.x - a2y * Zm.y + b2x * Zk.x + b2y * Zk.y,
                                         a2x * Zm.y + a2y * Zm.x - b2x * Zk.y + b2y * Zk.x);
      }
    }
    __syncthreads();
    fft2048r8<true>(X, Wl, tid);
    const ushortT* xn = projsT + ((size_t)(k * 4 + b) * 512 + c) * 4096;
    if (k < 2) {
      for (int m = tid; m < 2048; m += 256) {
        unsigned int pr = *(const unsigned int*)(xn + 2 * m);
        float2 a = X[PHYS(m)];
        X[PHYS(m)] = make_float2(a.x * scale * bf2f((ushortT)(pr & 0xffffu)),
                                 a.y * scale * bf2f((ushortT)(pr >> 16)));
      }
      __syncthreads();
      fft2048r8<false>(X, Wl, tid);
    } else {
      for (int m = tid; m < 2048; m += 256) {
        unsigned int pr = *(const unsigned int*)(xn + 2 * m);
        float2 a = X[PHYS(m)];
        *(float2*)(sig + 2 * m) = make_float2(a.x * scale * bf2f((ushortT)(pr & 0xffffu)),
                                              a.y * scale * bf2f((ushortT)(pr >> 16)));
      }
    }
  }
}

// ---------------- output GEMM (LDS-staged) ----------------

__launch_bounds__(256, 2)
__global__ void out_gemm(const float* __restrict__ vT, const float* __restrict__ oW,
                         const float* __restrict__ ob, float* __restrict__ out) {
  __shared__ float vs[64][68];    // [c][l], padded
  __shared__ float ows[64][36];   // [c][o], padded
  const int l0 = blockIdx.x * 64; // 256 blocks
  const int b = l0 >> 12;
  const int tid = threadIdx.x;
  const int l = tid & 63;
  const int og = (tid >> 6) * 8;
  float acc[8] = {};
  const float* vb = vT + (size_t)b * 2097152 + (l0 & 4095);
  const int cs = tid >> 2;            // staging row 0..63
  const int lq = (tid & 3) * 16;      // 16 floats per thread (4 x f32x4)
  const int oq = (tid & 3) * 8;
#pragma unroll 1
  for (int cc = 0; cc < 512; cc += 64) {
#pragma unroll
    for (int i = 0; i < 4; ++i)
      *(f32x4*)(&vs[cs][lq + i * 4]) = *(const f32x4*)(vb + (size_t)(cc + cs) * 4096 + lq + i * 4);
    *(f32x4*)(&ows[cs][oq])     = *(const f32x4*)(oW + (cc + cs) * 32 + oq);
    *(f32x4*)(&ows[cs][oq + 4]) = *(const f32x4*)(oW + (cc + cs) * 32 + oq + 4);
    __syncthreads();
#pragma unroll 8
    for (int c3 = 0; c3 < 64; ++c3) {
      float v = vs[c3][l];
#pragma unroll
      for (int j = 0; j < 8; ++j)
        acc[j] = fmaf(v, ows[c3][og + j], acc[j]);
    }
    __syncthreads();
  }
  float* op = out + (size_t)(l0 + l) * 32 + og;
  f32x4 r0, r1;
  r0[0] = acc[0] + ob[og];     r0[1] = acc[1] + ob[og + 1];
  r0[2] = acc[2] + ob[og + 2]; r0[3] = acc[3] + ob[og + 3];
  r1[0] = acc[4] + ob[og + 4]; r1[1] = acc[5] + ob[og + 5];
  r1[2] = acc[6] + ob[og + 6]; r1[3] = acc[7] + ob[og + 7];
  *(f32x4*)op = r0;
  *(f32x4*)(op + 4) = r1;
}

// ---------------- diagnostics ----------------

__global__ void ws_sentinel(float* __restrict__ out) {
  if (threadIdx.x == 0) out[0] = -31337.0f;
}

// ---------------- launch ----------------

extern "C" void kernel_launch(void* const* d_in, const int* in_sizes, int n_in,
                              void* d_out, int out_size, void* d_ws, size_t ws_size,
                              hipStream_t stream) {
  (void)in_sizes; (void)n_in; (void)out_size;
  const float* u  = (const float*)d_in[0];
  const float* pW = (const float*)d_in[1];
  const float* pb = (const float*)d_in[2];
  const float* cW = (const float*)d_in[3];
  const float* cb = (const float*)d_in[4];
  const float* fW = (const float*)d_in[5];
  const float* fb = (const float*)d_in[6];
  const float* oW = (const float*)d_in[7];
  const float* ob = (const float*)d_in[8];
  float* out = (float*)d_out;

  char* ws = (char*)d_ws;
  // persistent region
  ushortT* Upad   = (ushortT*)(ws);                    // 16,785,408
  ushortT* cWf    = (ushortT*)(ws + 16785408);         //  6,291,456
  float*   biasC  = (float*)  (ws + 23076864);         //      8,192
  float*   pbC0   = (float*)  (ws + 23085056);         //      8,192
  float*   pbC2   = (float*)  (ws + 23093248);         //      8,192
  float2*  Wg     = (float2*) (ws + 23101440);         //     16,384
  float2*  Sg     = (float2*) (ws + 23117824);         //      8,192
  float2*  Hf     = (float2*) (ws + 23126016);         // 25,264,128 (1536 x HSTR c64)
  float*   vT     = (float*)  (ws + 48390144);         // 33,554,432
  ushortT* projsT = (ushortT*)(ws + 81944576);         // 50,331,648
  const size_t total = 132276224;                      // 126.2 MiB
  // scratch overlay on [vT, end) — all dead before gemm_conv8 writes vT/projsT
  char* S = (char*)vT;
  ushortT* Wt     = (ushortT*)(S);                     // 25,165,824
  ushortT* pW_bf  = (ushortT*)(S + 25165824);          //  2,097,152
  float*   hT     = (float*)  (S + 27262976);          // 25,165,824 -> ends 52,428,800 (< 83,886,080)

  if (total > ws_size) {
    ws_sentinel<<<1, 64, 0, stream>>>(out);
    return;
  }

  convert_u_pad<<<8208, 256, 0, stream>>>(u, Upad);
  cast_flat<<<1024, 256, 0, stream>>>(pW, pW_bf);
  cwt_pbc<<<2048, 256, 0, stream>>>(cW, pb, cb, Wt, biasC, pbC0, pbC2);
  fill_tabs<<<12, 256, 0, stream>>>(Wg, Sg);
  gemm_fold<<<dim3(16, 4, 3), 256, 0, stream>>>(Wt, pW_bf, cWf);        // Wt,pW_bf dead after
  h_kernel<<<dim3(64, 12), 256, 0, stream>>>(fW, fb, hT);
  fft_filter_r<<<1536, 256, 0, stream>>>(hT, Wg, Hf);                   // hT dead after
  gemm_conv8<<<512, 512, 0, stream>>>(Upad, cWf, biasC, pbC0, pbC2, vT, projsT);
  fft_conv3<<<2048, 256, 0, stream>>>(vT, projsT, Hf, Wg, Sg);
  out_gemm<<<256, 256, 0, stream>>>(vT, oW, ob, out);
}